// Round 1
// baseline (373.931 us; speedup 1.0000x reference)
//
#include <hip/hip_runtime.h>

typedef unsigned short u16;
typedef unsigned int u32;
typedef unsigned long long u64;
typedef __bf16 bf16x8 __attribute__((ext_vector_type(8)));
typedef float f32x4 __attribute__((ext_vector_type(4)));

union FragAB {
  bf16x8 v;
  u16 u[8];
  u64 d2[2];
};

__device__ __forceinline__ u16 f2bf(float f) {
  u32 u = __builtin_bit_cast(u32, f);
  u += 0x7fffu + ((u >> 16) & 1u);
  return (u16)(u >> 16);
}

// ---------------- fp32 -> bf16 elementwise ----------------
__global__ __launch_bounds__(256) void conv_bf16_kernel(const float* __restrict__ in,
                                                        u16* __restrict__ out, int n4) {
  int i = blockIdx.x * 256 + threadIdx.x;
  if (i >= n4) return;
  float4 v = ((const float4*)in)[i];
  u32 lo = (u32)f2bf(v.x) | ((u32)f2bf(v.y) << 16);
  u32 hi = (u32)f2bf(v.z) | ((u32)f2bf(v.w) << 16);
  ((u32*)out)[2 * i] = lo;
  ((u32*)out)[2 * i + 1] = hi;
}

// ---------------- transpose + convert: out[n][k] = bf16(in[k][n]) ----------------
__global__ __launch_bounds__(256) void tconv_kernel(const float* __restrict__ in,
                                                    u16* __restrict__ out, int K, int N) {
  __shared__ float tile[32][33];
  int col = threadIdx.x & 31;
  int row0 = threadIdx.x >> 5;
  int kb = blockIdx.y * 32, nb = blockIdx.x * 32;
#pragma unroll
  for (int i = 0; i < 4; i++) {
    int r = row0 + i * 8;
    tile[r][col] = in[(size_t)(kb + r) * N + nb + col];
  }
  __syncthreads();
#pragma unroll
  for (int i = 0; i < 4; i++) {
    int r = row0 + i * 8;
    out[(size_t)(nb + r) * K + kb + col] = f2bf(tile[col][r]);
  }
}

// ---------------- gate: lgt[h][t] = log_sigmoid(off + hs[t]·Wg[:,h]) ----------------
__global__ __launch_bounds__(256) void gate_kernel(const float* __restrict__ hs,
                                                   const float* __restrict__ Wg,
                                                   float* __restrict__ lgt) {
  int lane = threadIdx.x & 63, wid = threadIdx.x >> 6;
  int t = blockIdx.x * 4 + wid;
  float acc[8] = {0.f, 0.f, 0.f, 0.f, 0.f, 0.f, 0.f, 0.f};
  for (int c = lane; c < 2048; c += 64) {
    float x = hs[(size_t)t * 2048 + c];
    float4 w0 = *(const float4*)&Wg[c * 8];
    float4 w1 = *(const float4*)&Wg[c * 8 + 4];
    acc[0] += x * w0.x; acc[1] += x * w0.y; acc[2] += x * w0.z; acc[3] += x * w0.w;
    acc[4] += x * w1.x; acc[5] += x * w1.y; acc[6] += x * w1.z; acc[7] += x * w1.w;
  }
#pragma unroll
  for (int h = 0; h < 8; h++) {
    float v = acc[h];
    for (int m = 1; m < 64; m <<= 1) v += __shfl_xor(v, m, 64);
    if (lane == 0) {
      float x = 6.906768f + v;
      lgt[h * 2048 + t] = -log1pf(__expf(-x));
    }
  }
}

// ---------------- inclusive cumsum over t, per head ----------------
__global__ __launch_bounds__(256) void cumsum_kernel(const float* __restrict__ lgt,
                                                     float* __restrict__ logG) {
  int h = blockIdx.x;
  __shared__ float buf[2048];
  for (int i = threadIdx.x; i < 2048; i += 256) buf[i] = lgt[h * 2048 + i];
  __syncthreads();
  for (int off = 1; off < 2048; off <<= 1) {
    float tmp[8];
#pragma unroll
    for (int j = 0; j < 8; j++) {
      int i = threadIdx.x + j * 256;
      tmp[j] = (i >= off) ? buf[i - off] : 0.f;
    }
    __syncthreads();
#pragma unroll
    for (int j = 0; j < 8; j++) {
      int i = threadIdx.x + j * 256;
      buf[i] += tmp[j];
    }
    __syncthreads();
  }
  for (int i = threadIdx.x; i < 2048; i += 256) logG[h * 2048 + i] = buf[i];
}

// ---------------- bf16 MFMA GEMM: C[m][n] = sum_k A[m][k]*BT[n][k] (+bias) ----------------
template <bool F32OUT>
__global__ __launch_bounds__(256) void gemm_bf16(const u16* __restrict__ A,
                                                 const u16* __restrict__ BT,
                                                 void* __restrict__ Cv,
                                                 const float* __restrict__ bias,
                                                 int M, int N, int K) {
  (void)M;
  __shared__ __align__(16) u16 As[128 * 40];
  __shared__ __align__(16) u16 Bs[128 * 40];
  const int tid = threadIdx.x;
  const int lane = tid & 63, wid = tid >> 6;
  const int m0 = blockIdx.x * 128, n0 = blockIdx.y * 128;
  const int wr = wid >> 1, wc = wid & 1;
  const int l15 = lane & 15, kg = lane >> 4;

  f32x4 acc[4][4];
#pragma unroll
  for (int i = 0; i < 4; i++)
#pragma unroll
    for (int j = 0; j < 4; j++) acc[i][j] = f32x4{0.f, 0.f, 0.f, 0.f};

  const int srow = tid >> 1;
  const int scol = (tid & 1) * 16;
  const u16* Ag = A + (size_t)(m0 + srow) * K + scol;
  const u16* Bg = BT + (size_t)(n0 + srow) * K + scol;

  for (int k0 = 0; k0 < K; k0 += 32) {
    *(uint4*)&As[srow * 40 + scol] = *(const uint4*)(Ag + k0);
    *(uint4*)&As[srow * 40 + scol + 8] = *(const uint4*)(Ag + k0 + 8);
    *(uint4*)&Bs[srow * 40 + scol] = *(const uint4*)(Bg + k0);
    *(uint4*)&Bs[srow * 40 + scol + 8] = *(const uint4*)(Bg + k0 + 8);
    __syncthreads();

    FragAB af[4], bfr[4];
#pragma unroll
    for (int mt = 0; mt < 4; mt++) {
      int row = wr * 64 + mt * 16 + l15;
      af[mt].d2[0] = *(const u64*)&As[row * 40 + 4 * kg];
      af[mt].d2[1] = *(const u64*)&As[row * 40 + 16 + 4 * kg];
    }
#pragma unroll
    for (int nt = 0; nt < 4; nt++) {
      int row = wc * 64 + nt * 16 + l15;
      bfr[nt].d2[0] = *(const u64*)&Bs[row * 40 + 4 * kg];
      bfr[nt].d2[1] = *(const u64*)&Bs[row * 40 + 16 + 4 * kg];
    }
#pragma unroll
    for (int mt = 0; mt < 4; mt++)
#pragma unroll
      for (int nt = 0; nt < 4; nt++)
        acc[mt][nt] = __builtin_amdgcn_mfma_f32_16x16x32_bf16(af[mt].v, bfr[nt].v, acc[mt][nt], 0, 0, 0);
    __syncthreads();
  }

#pragma unroll
  for (int mt = 0; mt < 4; mt++) {
#pragma unroll
    for (int re = 0; re < 4; re++) {
      int m = m0 + wr * 64 + mt * 16 + kg * 4 + re;
#pragma unroll
      for (int nt = 0; nt < 4; nt++) {
        int n = n0 + wc * 64 + nt * 16 + l15;
        float v = acc[mt][nt][re];
        if constexpr (F32OUT) {
          ((float*)Cv)[(size_t)m * N + n] = v + bias[n];
        } else {
          ((u16*)Cv)[(size_t)m * N + n] = f2bf(v);
        }
      }
    }
  }
}

// ---------------- power attention (flash-style, linear accumulation) ----------------
// grid: (32 q-tiles, 16 q-heads); block: 256 (4 waves, 16 q-rows per wave)
__global__ __launch_bounds__(256) void power_attn(const u16* __restrict__ Q,
                                                  const u16* __restrict__ Kb,
                                                  const u16* __restrict__ Vb,
                                                  const float* __restrict__ logG,
                                                  u16* __restrict__ Y) {
  const int qt = 31 - (int)blockIdx.x;  // heavy blocks dispatched first
  const int hq = blockIdx.y;
  const int hk = hq >> 1;
  const int t0 = qt * 64;
  const int tid = threadIdx.x, lane = tid & 63, wid = tid >> 6;
  const int l15 = lane & 15, kg = lane >> 4;
  const int tw = t0 + wid * 16;
  const int myT = tw + l15;

  __shared__ __align__(16) u16 Ks[64 * 128];   // K tile, row-major, XOR-swizzled
  __shared__ __align__(16) u16 Vt[128 * 64];   // V^T tile, XOR-swizzled
  __shared__ float lgS[64];

  // Q fragments in registers (B-operand of S^T mfma): Q[t=tw+l15][d]
  FragAB qf[4];
  const u16* qrow = Q + (size_t)myT * 2048 + hq * 128;
#pragma unroll
  for (int ks = 0; ks < 4; ks++) {
    qf[ks].d2[0] = *(const u64*)(qrow + ks * 32 + 4 * kg);
    qf[ks].d2[1] = *(const u64*)(qrow + ks * 32 + 16 + 4 * kg);
  }
  const float lgt = logG[hk * 2048 + myT];
  const float scale = 0.08838834764831845f;  // 1/sqrt(128)

  f32x4 yacc[8];
#pragma unroll
  for (int i = 0; i < 8; i++) yacc[i] = f32x4{0.f, 0.f, 0.f, 0.f};
  float nacc = 0.f;

  const int ntiles = qt + 1;
  for (int it = 0; it < ntiles; it++) {
    int s0 = it * 64;
    __syncthreads();  // protect LDS from previous iteration's readers
    {  // stage K: 64 x 128, swizzle elem ^= (row&7)<<3
      int row = tid >> 2, q4 = tid & 3;
      const u16* kr = Kb + (size_t)(s0 + row) * 1024 + hk * 128 + q4 * 32;
      u16* dst = &Ks[row * 128];
      int sw = (row & 7) << 3;
#pragma unroll
      for (int i = 0; i < 4; i++) {
        int col = q4 * 32 + i * 8;
        *(uint4*)&dst[col ^ sw] = *(const uint4*)(kr + i * 8);
      }
    }
    {  // stage V transposed: Vt[d][s], pairs (s,s+1) packed as u32
      int sp = tid >> 3;
      int dg = tid & 7;
      int s = 2 * sp;
      const u16* vr0 = Vb + (size_t)(s0 + s) * 1024 + hk * 128;
      const u16* vr1 = vr0 + 1024;
#pragma unroll
      for (int half = 0; half < 2; half++) {
        int d0 = (dg + 8 * half) * 8;
        uint4 va = *(const uint4*)(vr0 + d0);
        uint4 vb2 = *(const uint4*)(vr1 + d0);
        const u32* pa_ = (const u32*)&va;
        const u32* pb_ = (const u32*)&vb2;
#pragma unroll
        for (int i = 0; i < 8; i++) {
          u32 lo = (pa_[i >> 1] >> ((i & 1) * 16)) & 0xffffu;
          u32 hi = (pb_[i >> 1] >> ((i & 1) * 16)) & 0xffffu;
          int d = d0 + i;
          int idx = (d * 64 + s) ^ (((d ^ (d >> 3)) & 7) << 2);
          *(u32*)&Vt[idx] = (hi << 16) | lo;
        }
      }
    }
    if (tid < 64) lgS[tid] = logG[hk * 2048 + s0 + tid];
    __syncthreads();

    // S^T = K · Q^T : D[row=s_local][col=t]
    f32x4 sacc[4];
#pragma unroll
    for (int mt = 0; mt < 4; mt++) {
      sacc[mt] = f32x4{0.f, 0.f, 0.f, 0.f};
      int row = mt * 16 + l15;
      int sw = (row & 7) << 3;
      const u16* kbp = &Ks[row * 128];
#pragma unroll
      for (int ks = 0; ks < 4; ks++) {
        FragAB af;
        af.d2[0] = *(const u64*)&kbp[(ks * 32 + 4 * kg) ^ sw];
        af.d2[1] = *(const u64*)&kbp[(ks * 32 + 16 + 4 * kg) ^ sw];
        sacc[mt] = __builtin_amdgcn_mfma_f32_16x16x32_bf16(af.v, qf[ks].v, sacc[mt], 0, 0, 0);
      }
    }

    // gate + square + causal mask + pack P into PV A-fragments (direct reg reuse)
    FragAB pa[2];
#pragma unroll
    for (int mt = 0; mt < 4; mt++) {
#pragma unroll
      for (int r = 0; r < 4; r++) {
        int sl = mt * 16 + kg * 4 + r;
        int s = s0 + sl;
        float qk = sacc[mt][r] * scale;
        float p = qk * qk * __expf(lgt - lgS[sl]);
        p = (s <= myT) ? p : 0.0f;
        nacc += p;
        pa[mt >> 1].u[(mt & 1) * 4 + r] = f2bf(p);
      }
    }

    // Y += P · V
#pragma unroll
    for (int nt = 0; nt < 8; nt++) {
      int d = nt * 16 + l15;
      int swv = ((d ^ (d >> 3)) & 7) << 2;
      const u16* vbp = &Vt[d * 64];
#pragma unroll
      for (int ksv = 0; ksv < 2; ksv++) {
        FragAB bfr;
        bfr.d2[0] = *(const u64*)&vbp[(ksv * 32 + 4 * kg) ^ swv];
        bfr.d2[1] = *(const u64*)&vbp[(ksv * 32 + 16 + 4 * kg) ^ swv];
        yacc[nt] = __builtin_amdgcn_mfma_f32_16x16x32_bf16(pa[ksv].v, bfr.v, yacc[nt], 0, 0, 0);
      }
    }
  }

  // reduce norm across the 4 lane-groups holding the same t
  float nfull = nacc;
  nfull += __shfl_xor(nfull, 16, 64);
  nfull += __shfl_xor(nfull, 32, 64);
  nfull += 1e-6f;

#pragma unroll
  for (int re = 0; re < 4; re++) {
    float nr = __shfl(nfull, kg * 4 + re, 64);
    float inv = 1.0f / nr;
    int trow = tw + kg * 4 + re;
#pragma unroll
    for (int nt = 0; nt < 8; nt++) {
      Y[(size_t)trow * 2048 + hq * 128 + nt * 16 + l15] = f2bf(yacc[nt][re] * inv);
    }
  }
}

// ---------------- launch ----------------
extern "C" void kernel_launch(void* const* d_in, const int* in_sizes, int n_in,
                              void* d_out, int out_size, void* d_ws, size_t ws_size,
                              hipStream_t stream) {
  (void)in_sizes; (void)n_in; (void)out_size; (void)ws_size;
  const float* hs = (const float*)d_in[0];
  const float* Wq = (const float*)d_in[1];
  const float* Wk = (const float*)d_in[2];
  const float* Wv = (const float*)d_in[3];
  const float* Wg = (const float*)d_in[4];
  const float* Wc = (const float*)d_in[5];
  const float* bc = (const float*)d_in[6];
  float* out = (float*)d_out;

  char* ws = (char*)d_ws;
  const size_t MB = 1024 * 1024;
  u16* slotA = (u16*)(ws);               // 8MB: WqT -> WkT -> WvT -> WcT (sequential reuse)
  u16* hs_bf = (u16*)(ws + 8 * MB);      // 8MB: hs_bf, later y_bf
  u16* q_bf  = (u16*)(ws + 16 * MB);     // 8MB
  u16* k_bf  = (u16*)(ws + 24 * MB);     // 4MB
  u16* v_bf  = (u16*)(ws + 28 * MB);     // 4MB
  float* lgt  = (float*)(ws + 32 * MB);           // 64KB
  float* logG = (float*)(ws + 32 * MB + 65536);   // 64KB
  u16* y_bf = hs_bf;

  conv_bf16_kernel<<<4096, 256, 0, stream>>>(hs, hs_bf, 2048 * 2048 / 4);

  tconv_kernel<<<dim3(64, 64), 256, 0, stream>>>(Wq, slotA, 2048, 2048);
  gemm_bf16<false><<<dim3(16, 16), 256, 0, stream>>>(hs_bf, slotA, q_bf, nullptr, 2048, 2048, 2048);

  tconv_kernel<<<dim3(32, 64), 256, 0, stream>>>(Wk, slotA, 2048, 1024);
  gemm_bf16<false><<<dim3(16, 8), 256, 0, stream>>>(hs_bf, slotA, k_bf, nullptr, 2048, 1024, 2048);

  tconv_kernel<<<dim3(32, 64), 256, 0, stream>>>(Wv, slotA, 2048, 1024);
  gemm_bf16<false><<<dim3(16, 8), 256, 0, stream>>>(hs_bf, slotA, v_bf, nullptr, 2048, 1024, 2048);

  gate_kernel<<<512, 256, 0, stream>>>(hs, Wg, lgt);
  cumsum_kernel<<<8, 256, 0, stream>>>(lgt, logG);

  tconv_kernel<<<dim3(64, 64), 256, 0, stream>>>(Wc, slotA, 2048, 2048);

  power_attn<<<dim3(32, 16), 256, 0, stream>>>(q_bf, k_bf, v_bf, logG, y_bf);

  gemm_bf16<true><<<dim3(16, 16), 256, 0, stream>>>(y_bf, slotA, out, bc, 2048, 2048, 2048);
}

// Round 2
// 275.542 us; speedup vs baseline: 1.3571x; 1.3571x over previous
//
#include <hip/hip_runtime.h>

typedef unsigned short u16;
typedef unsigned int u32;
typedef unsigned long long u64;
typedef __bf16 bf16x8 __attribute__((ext_vector_type(8)));
typedef float f32x4 __attribute__((ext_vector_type(4)));

union FragAB {
  bf16x8 v;
  u16 u[8];
  u64 d2[2];
};

__device__ __forceinline__ u16 f2bf(float f) {
  u32 u = __builtin_bit_cast(u32, f);
  u += 0x7fffu + ((u >> 16) & 1u);
  return (u16)(u >> 16);
}

__device__ __forceinline__ void gload_lds16(const void* g, void* l) {
  __builtin_amdgcn_global_load_lds((__attribute__((address_space(1))) void*)g,
                                   (__attribute__((address_space(3))) void*)l, 16, 0, 0);
}

// ---------------- fp32 -> bf16 elementwise ----------------
__global__ __launch_bounds__(256) void conv_bf16_kernel(const float* __restrict__ in,
                                                        u16* __restrict__ out, int n4) {
  int i = blockIdx.x * 256 + threadIdx.x;
  if (i >= n4) return;
  float4 v = ((const float4*)in)[i];
  u32 lo = (u32)f2bf(v.x) | ((u32)f2bf(v.y) << 16);
  u32 hi = (u32)f2bf(v.z) | ((u32)f2bf(v.w) << 16);
  ((u32*)out)[2 * i] = lo;
  ((u32*)out)[2 * i + 1] = hi;
}

// ---------------- transpose + convert: out[n][k] = bf16(in[k][n]) ----------------
__global__ __launch_bounds__(256) void tconv_kernel(const float* __restrict__ in,
                                                    u16* __restrict__ out, int K, int N) {
  __shared__ float tile[32][33];
  int col = threadIdx.x & 31;
  int row0 = threadIdx.x >> 5;
  int kb = blockIdx.y * 32, nb = blockIdx.x * 32;
#pragma unroll
  for (int i = 0; i < 4; i++) {
    int r = row0 + i * 8;
    tile[r][col] = in[(size_t)(kb + r) * N + nb + col];
  }
  __syncthreads();
#pragma unroll
  for (int i = 0; i < 4; i++) {
    int r = row0 + i * 8;
    out[(size_t)(nb + r) * K + kb + col] = f2bf(tile[col][r]);
  }
}

// ---------------- gate: lgt[h][t] = log_sigmoid(off + hs[t]·Wg[:,h]) ----------------
__global__ __launch_bounds__(256) void gate_kernel(const float* __restrict__ hs,
                                                   const float* __restrict__ Wg,
                                                   float* __restrict__ lgt) {
  int lane = threadIdx.x & 63, wid = threadIdx.x >> 6;
  int t = blockIdx.x * 4 + wid;
  float acc[8] = {0.f, 0.f, 0.f, 0.f, 0.f, 0.f, 0.f, 0.f};
  for (int c = lane; c < 2048; c += 64) {
    float x = hs[(size_t)t * 2048 + c];
    float4 w0 = *(const float4*)&Wg[c * 8];
    float4 w1 = *(const float4*)&Wg[c * 8 + 4];
    acc[0] += x * w0.x; acc[1] += x * w0.y; acc[2] += x * w0.z; acc[3] += x * w0.w;
    acc[4] += x * w1.x; acc[5] += x * w1.y; acc[6] += x * w1.z; acc[7] += x * w1.w;
  }
#pragma unroll
  for (int h = 0; h < 8; h++) {
    float v = acc[h];
    for (int m = 1; m < 64; m <<= 1) v += __shfl_xor(v, m, 64);
    if (lane == 0) {
      float x = 6.906768f + v;
      lgt[h * 2048 + t] = -log1pf(__expf(-x));
    }
  }
}

// ---------------- inclusive cumsum over t, per head ----------------
__global__ __launch_bounds__(256) void cumsum_kernel(const float* __restrict__ lgt,
                                                     float* __restrict__ logG) {
  int h = blockIdx.x;
  __shared__ float buf[2048];
  for (int i = threadIdx.x; i < 2048; i += 256) buf[i] = lgt[h * 2048 + i];
  __syncthreads();
  for (int off = 1; off < 2048; off <<= 1) {
    float tmp[8];
#pragma unroll
    for (int j = 0; j < 8; j++) {
      int i = threadIdx.x + j * 256;
      tmp[j] = (i >= off) ? buf[i - off] : 0.f;
    }
    __syncthreads();
#pragma unroll
    for (int j = 0; j < 8; j++) {
      int i = threadIdx.x + j * 256;
      buf[i] += tmp[j];
    }
    __syncthreads();
  }
  for (int i = threadIdx.x; i < 2048; i += 256) logG[h * 2048 + i] = buf[i];
}

// ---------------- bf16 MFMA GEMM (m97-style): C[m][n] = sum_k A[m][k]*BT[n][k] ----------------
// 128x128 tile, BK=64, 8 waves (512 thr), global_load_lds staging with 16B XOR source-swizzle.
template <bool F32OUT>
__global__ __launch_bounds__(512) void gemm_bf16(const u16* __restrict__ A,
                                                 const u16* __restrict__ BT,
                                                 void* __restrict__ Cv,
                                                 const float* __restrict__ bias,
                                                 int N, int K) {
  __shared__ __align__(16) u16 As[128 * 64];
  __shared__ __align__(16) u16 Bs[128 * 64];
  const int tid = threadIdx.x;
  const int lane = tid & 63, wid = tid >> 6;
  const int m0 = blockIdx.x * 128, n0 = blockIdx.y * 128;
  const int wr = wid >> 2, wc = wid & 3;
  const int l15 = lane & 15, kg = lane >> 4;

  f32x4 acc[4][2];
#pragma unroll
  for (int i = 0; i < 4; i++)
#pragma unroll
    for (int j = 0; j < 2; j++) acc[i][j] = f32x4{0.f, 0.f, 0.f, 0.f};

  // staging: 1024 16B-chunks per matrix; wave issues 2 per matrix.
  // chunk -> row = c>>3, dest-unit = c&7; source unit = destunit ^ (row&7)
  const int ch0 = (wid * 2) * 64 + lane;
  const int ch1 = ch0 + 64;
  const int r0 = ch0 >> 3, u0 = (ch0 & 7) ^ (r0 & 7);
  const int r1 = ch1 >> 3, u1 = (ch1 & 7) ^ (r1 & 7);
  const u16* Asrc0 = A + (size_t)(m0 + r0) * K + u0 * 8;
  const u16* Asrc1 = A + (size_t)(m0 + r1) * K + u1 * 8;
  const u16* Bsrc0 = BT + (size_t)(n0 + r0) * K + u0 * 8;
  const u16* Bsrc1 = BT + (size_t)(n0 + r1) * K + u1 * 8;
  u16* Adst0 = As + (wid * 2) * 512;
  u16* Bdst0 = Bs + (wid * 2) * 512;

  for (int k0 = 0; k0 < K; k0 += 64) {
    __syncthreads();
    gload_lds16(Asrc0 + k0, Adst0);
    gload_lds16(Asrc1 + k0, Adst0 + 512);
    gload_lds16(Bsrc0 + k0, Bdst0);
    gload_lds16(Bsrc1 + k0, Bdst0 + 512);
    __syncthreads();

#pragma unroll
    for (int ks = 0; ks < 2; ks++) {
      FragAB af[4], bfr[2];
      const int ul = ks * 4 + (kg >> 1);
#pragma unroll
      for (int mt = 0; mt < 4; mt++) {
        int row = wr * 64 + mt * 16 + l15;
        int sw = row & 7;
        const u16* p = &As[row * 64 + (kg & 1) * 4];
        af[mt].d2[0] = *(const u64*)&p[(ul ^ sw) << 3];
        af[mt].d2[1] = *(const u64*)&p[((ul + 2) ^ sw) << 3];
      }
#pragma unroll
      for (int nt = 0; nt < 2; nt++) {
        int row = wc * 32 + nt * 16 + l15;
        int sw = row & 7;
        const u16* p = &Bs[row * 64 + (kg & 1) * 4];
        bfr[nt].d2[0] = *(const u64*)&p[(ul ^ sw) << 3];
        bfr[nt].d2[1] = *(const u64*)&p[((ul + 2) ^ sw) << 3];
      }
#pragma unroll
      for (int mt = 0; mt < 4; mt++)
#pragma unroll
        for (int nt = 0; nt < 2; nt++)
          acc[mt][nt] = __builtin_amdgcn_mfma_f32_16x16x32_bf16(af[mt].v, bfr[nt].v, acc[mt][nt], 0, 0, 0);
    }
  }

#pragma unroll
  for (int mt = 0; mt < 4; mt++) {
#pragma unroll
    for (int re = 0; re < 4; re++) {
      int m = m0 + wr * 64 + mt * 16 + kg * 4 + re;
#pragma unroll
      for (int nt = 0; nt < 2; nt++) {
        int n = n0 + wc * 32 + nt * 16 + l15;
        float v = acc[mt][nt][re];
        if constexpr (F32OUT) {
          ((float*)Cv)[(size_t)m * N + n] = v + bias[n];
        } else {
          ((u16*)Cv)[(size_t)m * N + n] = f2bf(v);
        }
      }
    }
  }
}

// ---------------- power attention (flash-style, linear accumulation, split-K) ----------------
// grid: (64 = 32 q-tiles x 2 halves, 16 q-heads); block: 256 (4 waves, 16 q-rows per wave)
__global__ __launch_bounds__(256) void power_attn(const u16* __restrict__ Q,
                                                  const u16* __restrict__ KV,
                                                  const float* __restrict__ logG,
                                                  float* __restrict__ y0p,
                                                  float* __restrict__ y1p,
                                                  float* __restrict__ npart) {
  const int bx = blockIdx.x;
  const int qt = 31 - (bx >> 1);  // heavy blocks dispatched first
  const int half = bx & 1;
  const int hq = blockIdx.y;
  const int hk = hq >> 1;
  const int t0 = qt * 64;
  const int tid = threadIdx.x, lane = tid & 63, wid = tid >> 6;
  const int l15 = lane & 15, kg = lane >> 4;
  const int tw = t0 + wid * 16;
  const int myT = tw + l15;

  __shared__ __align__(16) u16 Ks[64 * 128];   // K tile, row-major, XOR-swizzled (16B units)
  __shared__ __align__(16) u16 Vt[128 * 68];   // V^T tile, pad-stride 68
  __shared__ float expS[64];

  FragAB qf[4];
  const u16* qrow = Q + (size_t)myT * 2048 + hq * 128;
#pragma unroll
  for (int ks = 0; ks < 4; ks++) {
    qf[ks].d2[0] = *(const u64*)(qrow + ks * 32 + 4 * kg);
    qf[ks].d2[1] = *(const u64*)(qrow + ks * 32 + 16 + 4 * kg);
  }
  const float scale = 0.08838834764831845f;  // 1/sqrt(128)
  const float elg = __expf(logG[hk * 2048 + myT]);

  const u16* Kbase = KV + hk * 128;
  const u16* Vbase = KV + 1024 + hk * 128;
  const int chK = (wid * 4) * 64 + lane;

  f32x4 yacc[8];
#pragma unroll
  for (int i = 0; i < 8; i++) yacc[i] = f32x4{0.f, 0.f, 0.f, 0.f};
  float nacc = 0.f;

  const int ntiles = qt + 1;
  const int nh = (ntiles + 1) >> 1;
  const int itBeg = half ? nh : 0;
  const int itEnd = half ? ntiles : nh;

  for (int it = itBeg; it < itEnd; it++) {
    const int s0 = it * 64;
    __syncthreads();  // protect LDS from previous iteration's readers
    // stage K via global_load_lds, source pre-swizzled (unit ^= row&7)
#pragma unroll
    for (int j = 0; j < 4; j++) {
      int ch = chK + j * 64;
      int row = ch >> 4, u = ch & 15;
      int us = u ^ (row & 7);
      gload_lds16(Kbase + (size_t)(s0 + row) * 2048 + us * 8, Ks + (size_t)(wid * 4 + j) * 512);
    }
    {  // stage V transposed: Vt[d][s] pad-stride 68, v_perm packing
      int sp = tid >> 3;
      int dg = tid & 7;
      int s = 2 * sp;
      const u16* vr0 = Vbase + (size_t)(s0 + s) * 2048;
      const u16* vr1 = vr0 + 2048;
#pragma unroll
      for (int hh = 0; hh < 2; hh++) {
        int d0 = (dg + 8 * hh) * 8;
        uint4 va = *(const uint4*)(vr0 + d0);
        uint4 vb2 = *(const uint4*)(vr1 + d0);
        const u32* pa_ = (const u32*)&va;
        const u32* pb_ = (const u32*)&vb2;
#pragma unroll
        for (int x = 0; x < 4; x++) {
          u32 lo_pair = __builtin_amdgcn_perm(pb_[x], pa_[x], 0x05040100u);
          u32 hi_pair = __builtin_amdgcn_perm(pb_[x], pa_[x], 0x07060302u);
          int d = d0 + 2 * x;
          *(u32*)&Vt[d * 68 + s] = lo_pair;
          *(u32*)&Vt[(d + 1) * 68 + s] = hi_pair;
        }
      }
    }
    if (tid < 64) expS[tid] = __expf(-logG[hk * 2048 + s0 + tid]);
    __syncthreads();

    // S^T = K · Q^T : D[row=s_local][col=t]
    f32x4 sacc[4];
#pragma unroll
    for (int mt = 0; mt < 4; mt++) {
      sacc[mt] = f32x4{0.f, 0.f, 0.f, 0.f};
      int row = mt * 16 + l15;
      int sw = (row & 7) << 3;
      const u16* kbp = &Ks[row * 128];
#pragma unroll
      for (int ks = 0; ks < 4; ks++) {
        FragAB af;
        af.d2[0] = *(const u64*)&kbp[(ks * 32 + 4 * kg) ^ sw];
        af.d2[1] = *(const u64*)&kbp[(ks * 32 + 16 + 4 * kg) ^ sw];
        sacc[mt] = __builtin_amdgcn_mfma_f32_16x16x32_bf16(af.v, qf[ks].v, sacc[mt], 0, 0, 0);
      }
    }

    // gate + square + (diagonal-only) causal mask + pack P into PV A-fragments
    const bool need_mask = (it == qt);
    FragAB pa[2];
#pragma unroll
    for (int mt = 0; mt < 4; mt++) {
#pragma unroll
      for (int r = 0; r < 4; r++) {
        int sl = mt * 16 + kg * 4 + r;
        float qk = sacc[mt][r] * scale;
        float p = qk * qk * elg * expS[sl];
        if (need_mask) p = (s0 + sl <= myT) ? p : 0.0f;
        nacc += p;
        pa[mt >> 1].u[(mt & 1) * 4 + r] = f2bf(p);
      }
    }

    // Y += P · V
#pragma unroll
    for (int nt = 0; nt < 8; nt++) {
      int d = nt * 16 + l15;
      const u16* vbp = &Vt[d * 68];
#pragma unroll
      for (int ksv = 0; ksv < 2; ksv++) {
        FragAB bfr;
        bfr.d2[0] = *(const u64*)&vbp[ksv * 32 + 4 * kg];
        bfr.d2[1] = *(const u64*)&vbp[ksv * 32 + 16 + 4 * kg];
        yacc[nt] = __builtin_amdgcn_mfma_f32_16x16x32_bf16(pa[ksv].v, bfr.v, yacc[nt], 0, 0, 0);
      }
    }
  }

  // reduce norm across the 4 lane-groups holding the same t
  float nfull = nacc;
  nfull += __shfl_xor(nfull, 16, 64);
  nfull += __shfl_xor(nfull, 32, 64);

  float* yp = half ? y1p : y0p;
  float* np = npart + half * (16 * 2048);
  if (lane < 16) np[hq * 2048 + tw + lane] = nfull;

#pragma unroll
  for (int re = 0; re < 4; re++) {
    int trow = tw + kg * 4 + re;
#pragma unroll
    for (int nt = 0; nt < 8; nt++) {
      yp[(size_t)trow * 2048 + hq * 128 + nt * 16 + l15] = yacc[nt][re];
    }
  }
}

// ---------------- combine split-K partials + normalize -> bf16 ----------------
__global__ __launch_bounds__(256) void combine_kernel(const float* __restrict__ y0,
                                                      const float* __restrict__ y1,
                                                      const float* __restrict__ npart,
                                                      u16* __restrict__ yb) {
  int i = blockIdx.x * 256 + threadIdx.x;  // float4 index over [2048][2048]
  int e0 = i << 2;
  int t = e0 >> 11;
  int hq = (e0 >> 7) & 15;
  float nn = npart[hq * 2048 + t] + npart[32768 + hq * 2048 + t] + 1e-6f;
  float inv = 1.0f / nn;
  float4 a = ((const float4*)y0)[i];
  float4 b = ((const float4*)y1)[i];
  u32 lo = (u32)f2bf((a.x + b.x) * inv) | ((u32)f2bf((a.y + b.y) * inv) << 16);
  u32 hi = (u32)f2bf((a.z + b.z) * inv) | ((u32)f2bf((a.w + b.w) * inv) << 16);
  ((u32*)yb)[2 * i] = lo;
  ((u32*)yb)[2 * i + 1] = hi;
}

// ---------------- launch ----------------
extern "C" void kernel_launch(void* const* d_in, const int* in_sizes, int n_in,
                              void* d_out, int out_size, void* d_ws, size_t ws_size,
                              hipStream_t stream) {
  (void)in_sizes; (void)n_in; (void)out_size; (void)ws_size;
  const float* hs = (const float*)d_in[0];
  const float* Wq = (const float*)d_in[1];
  const float* Wk = (const float*)d_in[2];
  const float* Wv = (const float*)d_in[3];
  const float* Wg = (const float*)d_in[4];
  const float* Wc = (const float*)d_in[5];
  const float* bc = (const float*)d_in[6];
  float* out = (float*)d_out;

  char* ws = (char*)d_ws;
  const size_t MB = 1024 * 1024;
  u16* slotA  = (u16*)(ws);             // 8MB: WqT then WcT
  u16* slotB  = (u16*)(ws + 8 * MB);    // 8MB: [WkT | WvT] stacked (merged kv weights)
  u16* hs_bf  = (u16*)(ws + 16 * MB);   // 8MB: hs_bf, later y_bf
  u16* q_bf   = (u16*)(ws + 24 * MB);   // 8MB
  u16* kv_bf  = (u16*)(ws + 32 * MB);   // 8MB: [k(1024) | v(1024)] per row
  float* y0p  = (float*)(ws + 40 * MB); // 16MB f32 partial (half 0)
  float* npart = (float*)(ws + 56 * MB);            // 256KB (2 halves x 16 x 2048)
  float* lgt  = (float*)(ws + 56 * MB + 262144);    // 64KB
  float* logG = (float*)(ws + 56 * MB + 327680);    // 64KB
  float* y1p = out;   // use d_out as scratch for half-1 partial (rewritten by final GEMM)
  u16* y_bf = hs_bf;

  conv_bf16_kernel<<<4096, 256, 0, stream>>>(hs, hs_bf, 2048 * 2048 / 4);

  tconv_kernel<<<dim3(64, 64), 256, 0, stream>>>(Wq, slotA, 2048, 2048);
  gemm_bf16<false><<<dim3(16, 16), 512, 0, stream>>>(hs_bf, slotA, q_bf, nullptr, 2048, 2048);

  tconv_kernel<<<dim3(32, 64), 256, 0, stream>>>(Wk, slotB, 2048, 1024);
  tconv_kernel<<<dim3(32, 64), 256, 0, stream>>>(Wv, slotB + (size_t)1024 * 2048, 2048, 1024);
  gemm_bf16<false><<<dim3(16, 16), 512, 0, stream>>>(hs_bf, slotB, kv_bf, nullptr, 2048, 2048);

  gate_kernel<<<512, 256, 0, stream>>>(hs, Wg, lgt);
  cumsum_kernel<<<8, 256, 0, stream>>>(lgt, logG);

  tconv_kernel<<<dim3(64, 64), 256, 0, stream>>>(Wc, slotA, 2048, 2048);

  power_attn<<<dim3(64, 16), 256, 0, stream>>>(q_bf, kv_bf, logG, y0p, y1p, npart);
  combine_kernel<<<4096, 256, 0, stream>>>(y0p, y1p, npart, y_bf);

  gemm_bf16<true><<<dim3(16, 16), 512, 0, stream>>>(y_bf, slotA, out, bc, 2048, 2048);
}

// Round 3
// 244.282 us; speedup vs baseline: 1.5307x; 1.1280x over previous
//
#include <hip/hip_runtime.h>

typedef unsigned short u16;
typedef unsigned int u32;
typedef unsigned long long u64;
typedef __bf16 bf16x8 __attribute__((ext_vector_type(8)));
typedef float f32x4 __attribute__((ext_vector_type(4)));

union FragAB {
  bf16x8 v;
  u16 u[8];
  u32 w[4];
  u64 d2[2];
};

__device__ __forceinline__ u16 f2bf(float f) {
  u32 u = __builtin_bit_cast(u32, f);
  u += 0x7fffu + ((u >> 16) & 1u);
  return (u16)(u >> 16);
}

__device__ __forceinline__ void gload_lds16(const void* g, void* l) {
  __builtin_amdgcn_global_load_lds((__attribute__((address_space(1))) void*)g,
                                   (__attribute__((address_space(3))) void*)l, 16, 0, 0);
}

// column permutation within each 32-group: fragment for (kg) becomes 16 contiguous bytes
// e = 8*((k&15)>>2) + 4*(k>>4) + (k&3)
__device__ __forceinline__ int permcol(int n) {
  int k = n & 31;
  return (n & ~31) | ((k & 12) << 1) | ((k & 16) >> 2) | (k & 3);
}

// ---------------- fp32 -> bf16 elementwise ----------------
__global__ __launch_bounds__(256) void conv_bf16_kernel(const float* __restrict__ in,
                                                        u16* __restrict__ out, int n4) {
  int i = blockIdx.x * 256 + threadIdx.x;
  if (i >= n4) return;
  float4 v = ((const float4*)in)[i];
  u32 lo = (u32)f2bf(v.x) | ((u32)f2bf(v.y) << 16);
  u32 hi = (u32)f2bf(v.z) | ((u32)f2bf(v.w) << 16);
  ((u32*)out)[2 * i] = lo;
  ((u32*)out)[2 * i + 1] = hi;
}

// ---------------- transpose + convert: out[n][k] = bf16(in[k][n]) ----------------
__global__ __launch_bounds__(256) void tconv_kernel(const float* __restrict__ in,
                                                    u16* __restrict__ out, int K, int N) {
  __shared__ float tile[32][33];
  int col = threadIdx.x & 31;
  int row0 = threadIdx.x >> 5;
  int kb = blockIdx.y * 32, nb = blockIdx.x * 32;
#pragma unroll
  for (int i = 0; i < 4; i++) {
    int r = row0 + i * 8;
    tile[r][col] = in[(size_t)(kb + r) * N + nb + col];
  }
  __syncthreads();
#pragma unroll
  for (int i = 0; i < 4; i++) {
    int r = row0 + i * 8;
    out[(size_t)(nb + r) * K + kb + col] = f2bf(tile[col][r]);
  }
}

// ---------------- gate: lgt[h][t] = log_sigmoid(off + hs[t]·Wg[:,h]) ----------------
__global__ __launch_bounds__(256) void gate_kernel(const float* __restrict__ hs,
                                                   const float* __restrict__ Wg,
                                                   float* __restrict__ lgt) {
  int lane = threadIdx.x & 63, wid = threadIdx.x >> 6;
  int t = blockIdx.x * 4 + wid;
  float acc[8] = {0.f, 0.f, 0.f, 0.f, 0.f, 0.f, 0.f, 0.f};
  for (int c = lane; c < 2048; c += 64) {
    float x = hs[(size_t)t * 2048 + c];
    float4 w0 = *(const float4*)&Wg[c * 8];
    float4 w1 = *(const float4*)&Wg[c * 8 + 4];
    acc[0] += x * w0.x; acc[1] += x * w0.y; acc[2] += x * w0.z; acc[3] += x * w0.w;
    acc[4] += x * w1.x; acc[5] += x * w1.y; acc[6] += x * w1.z; acc[7] += x * w1.w;
  }
#pragma unroll
  for (int h = 0; h < 8; h++) {
    float v = acc[h];
    for (int m = 1; m < 64; m <<= 1) v += __shfl_xor(v, m, 64);
    if (lane == 0) {
      float x = 6.906768f + v;
      lgt[h * 2048 + t] = -log1pf(__expf(-x));
    }
  }
}

// ---------------- inclusive cumsum over t, per head ----------------
__global__ __launch_bounds__(256) void cumsum_kernel(const float* __restrict__ lgt,
                                                     float* __restrict__ logG) {
  int h = blockIdx.x;
  __shared__ float buf[2048];
  for (int i = threadIdx.x; i < 2048; i += 256) buf[i] = lgt[h * 2048 + i];
  __syncthreads();
  for (int off = 1; off < 2048; off <<= 1) {
    float tmp[8];
#pragma unroll
    for (int j = 0; j < 8; j++) {
      int i = threadIdx.x + j * 256;
      tmp[j] = (i >= off) ? buf[i - off] : 0.f;
    }
    __syncthreads();
#pragma unroll
    for (int j = 0; j < 8; j++) {
      int i = threadIdx.x + j * 256;
      buf[i] += tmp[j];
    }
    __syncthreads();
  }
  for (int i = threadIdx.x; i < 2048; i += 256) logG[h * 2048 + i] = buf[i];
}

// ---------------- bf16 MFMA GEMM: C[m][n] = sum_k A[m][k]*BT[n][k] ----------------
// MODE: 1 = bf16 out, all columns permuted; 2 = bf16 out, permute n<1024 only; 3 = f32+bias
template <int MODE>
__global__ __launch_bounds__(512) void gemm_bf16(const u16* __restrict__ A,
                                                 const u16* __restrict__ BT,
                                                 void* __restrict__ Cv,
                                                 const float* __restrict__ bias,
                                                 int N, int K) {
  __shared__ __align__(16) u16 As[128 * 64];
  __shared__ __align__(16) u16 Bs[128 * 64];
  const int tid = threadIdx.x;
  const int lane = tid & 63, wid = tid >> 6;
  const int m0 = blockIdx.x * 128, n0 = blockIdx.y * 128;
  const int wr = wid >> 2, wc = wid & 3;
  const int l15 = lane & 15, kg = lane >> 4;

  f32x4 acc[4][2];
#pragma unroll
  for (int i = 0; i < 4; i++)
#pragma unroll
    for (int j = 0; j < 2; j++) acc[i][j] = f32x4{0.f, 0.f, 0.f, 0.f};

  const int ch0 = (wid * 2) * 64 + lane;
  const int ch1 = ch0 + 64;
  const int r0 = ch0 >> 3, u0 = (ch0 & 7) ^ (r0 & 7);
  const int r1 = ch1 >> 3, u1 = (ch1 & 7) ^ (r1 & 7);
  const u16* Asrc0 = A + (size_t)(m0 + r0) * K + u0 * 8;
  const u16* Asrc1 = A + (size_t)(m0 + r1) * K + u1 * 8;
  const u16* Bsrc0 = BT + (size_t)(n0 + r0) * K + u0 * 8;
  const u16* Bsrc1 = BT + (size_t)(n0 + r1) * K + u1 * 8;
  u16* Adst0 = As + (wid * 2) * 512;
  u16* Bdst0 = Bs + (wid * 2) * 512;

  for (int k0 = 0; k0 < K; k0 += 64) {
    __syncthreads();
    gload_lds16(Asrc0 + k0, Adst0);
    gload_lds16(Asrc1 + k0, Adst0 + 512);
    gload_lds16(Bsrc0 + k0, Bdst0);
    gload_lds16(Bsrc1 + k0, Bdst0 + 512);
    __syncthreads();

#pragma unroll
    for (int ks = 0; ks < 2; ks++) {
      FragAB af[4], bfr[2];
      const int ul = ks * 4 + (kg >> 1);
#pragma unroll
      for (int mt = 0; mt < 4; mt++) {
        int row = wr * 64 + mt * 16 + l15;
        int sw = row & 7;
        const u16* p = &As[row * 64 + (kg & 1) * 4];
        af[mt].d2[0] = *(const u64*)&p[(ul ^ sw) << 3];
        af[mt].d2[1] = *(const u64*)&p[((ul + 2) ^ sw) << 3];
      }
#pragma unroll
      for (int nt = 0; nt < 2; nt++) {
        int row = wc * 32 + nt * 16 + l15;
        int sw = row & 7;
        const u16* p = &Bs[row * 64 + (kg & 1) * 4];
        bfr[nt].d2[0] = *(const u64*)&p[(ul ^ sw) << 3];
        bfr[nt].d2[1] = *(const u64*)&p[((ul + 2) ^ sw) << 3];
      }
#pragma unroll
      for (int mt = 0; mt < 4; mt++)
#pragma unroll
        for (int nt = 0; nt < 2; nt++)
          acc[mt][nt] = __builtin_amdgcn_mfma_f32_16x16x32_bf16(af[mt].v, bfr[nt].v, acc[mt][nt], 0, 0, 0);
    }
  }

#pragma unroll
  for (int mt = 0; mt < 4; mt++) {
#pragma unroll
    for (int re = 0; re < 4; re++) {
      int m = m0 + wr * 64 + mt * 16 + kg * 4 + re;
#pragma unroll
      for (int nt = 0; nt < 2; nt++) {
        int n = n0 + wc * 32 + nt * 16 + l15;
        float v = acc[mt][nt][re];
        if constexpr (MODE == 3) {
          ((float*)Cv)[(size_t)m * N + n] = v + bias[n];
        } else {
          int nw = (MODE == 1 || (MODE == 2 && n < 1024)) ? permcol(n) : n;
          ((u16*)Cv)[(size_t)m * N + nw] = f2bf(v);
        }
      }
    }
  }
}

// ---------------- power attention: Q-tile 128, KV-tile 64, dbuf pipeline ----------------
// grid: 512 blocks (decoded -> hq, qt, half); block: 256 (4 waves, 2 col-groups each)
__global__ __launch_bounds__(256, 2) void power_attn(const u16* __restrict__ Q,
                                                     const u16* __restrict__ KV,
                                                     const float* __restrict__ logG,
                                                     float* __restrict__ y0p,
                                                     float* __restrict__ y1p,
                                                     float* __restrict__ npart) {
  __shared__ __align__(16) u16 Ks[2 * 64 * 128];
  __shared__ __align__(16) u16 Vt[2 * 128 * 64];
  __shared__ float eS[2 * 64];

  // XCD-aware decode: each XCD gets one kv-head pair; paired blocks sum to equal work
  const int raw = (int)blockIdx.x;
  const int orig = (raw & 7) * 64 + (raw >> 3);
  const int hq = orig >> 5;
  const int j_ = orig & 31;
  const int half = j_ & 1;
  const int bslot = j_ >> 1;
  const int qa = (bslot + (hq >> 1) * 3) & 15;
  const int qt = (hq & 1) ? (15 - qa) : qa;
  const int hk = hq >> 1;
  const int t0 = qt * 128;

  const int tid = threadIdx.x, lane = tid & 63, wid = tid >> 6;
  const int l15 = lane & 15, kg = lane >> 4;
  const int l7 = l15 & 7;

  // V-stage roles
  const int s4 = tid & 15, dgrp = tid >> 4;
  const int ubase = 4 * (s4 >> 3) + (s4 & 3);
  const int vhb = (s4 >> 2) & 1;

  const u16* Kbase = KV + hk * 128;
  const u16* Vbase = KV + 1024 + hk * 128 + dgrp * 8;
  const float* lgh = logG + hk * 2048;

  // Q fragments (permuted layout: frag = contiguous 16B) + per-row gate
  FragAB qf[2][4];
  float celg[2];
  int myT[2];
  const float scale2 = 0.0078125f;  // 1/128
#pragma unroll
  for (int cg = 0; cg < 2; cg++) {
    myT[cg] = t0 + wid * 16 + cg * 64 + l15;
    const u16* qrow = Q + (size_t)myT[cg] * 2048 + hq * 128;
#pragma unroll
    for (int ks = 0; ks < 4; ks++) qf[cg][ks].v = *(const bf16x8*)(qrow + ks * 32 + kg * 8);
    celg[cg] = scale2 * __expf(lgh[myT[cg]]);
  }

  f32x4 yacc[8][2];
#pragma unroll
  for (int i = 0; i < 8; i++)
#pragma unroll
    for (int c = 0; c < 2; c++) yacc[i][c] = f32x4{0.f, 0.f, 0.f, 0.f};
  float nacc[2] = {0.f, 0.f};

  const int itBeg = half ? (qt + 1) : 0;
  const int itEnd = half ? (2 * qt + 2) : (qt + 1);

  auto stageK = [&](int s0, int bb) {
#pragma unroll
    for (int c = 0; c < 4; c++) {
      int ch = (wid * 4 + c) * 64 + lane;
      int row = ch >> 4, du = ch & 15;
      int su = du ^ (row & 7);
      gload_lds16(Kbase + (size_t)(s0 + row) * 2048 + su * 8, &Ks[bb * 8192 + (wid * 4 + c) * 512]);
    }
  };
  auto loadV = [&](int s0, uint4* vr) {
#pragma unroll
    for (int r = 0; r < 4; r++) vr[r] = *(const uint4*)(Vbase + (size_t)(s0 + 4 * s4 + r) * 2048);
  };
  auto writeV = [&](int bb, const uint4* vr) {
    u16* vd = &Vt[bb * 8192];
    const u32* w0 = (const u32*)&vr[0];
    const u32* w1 = (const u32*)&vr[1];
    const u32* w2 = (const u32*)&vr[2];
    const u32* w3 = (const u32*)&vr[3];
#pragma unroll
    for (int i = 0; i < 8; i++) {
      u32 sel = (i & 1) ? 0x07060302u : 0x05040100u;
      u32 lo = __builtin_amdgcn_perm(w1[i >> 1], w0[i >> 1], sel);
      u32 hi = __builtin_amdgcn_perm(w3[i >> 1], w2[i >> 1], sel);
      int d = dgrp * 8 + i;
      int e = d * 64 + 8 * (ubase ^ i) + 4 * vhb;
      *(u64*)&vd[e] = (u64)lo | ((u64)hi << 32);
    }
  };

  {  // prologue: stage first tile into buf 0
    uint4 vr[4];
    stageK(itBeg * 64, 0);
    loadV(itBeg * 64, vr);
    float ee = (tid < 64) ? lgh[itBeg * 64 + tid] : 0.f;
    writeV(0, vr);
    if (tid < 64) eS[tid] = __expf(-ee);
  }
  __syncthreads();

  for (int it = itBeg; it < itEnd; it++) {
    const int cur = (it - itBeg) & 1;
    const int s0 = it * 64;
    const bool hasNext = (it + 1 < itEnd);
    uint4 vr[4];
    float ee = 0.f;
    if (hasNext) {  // phase A: issue next tile's loads (hidden under compute)
      stageK(s0 + 64, cur ^ 1);
      loadV(s0 + 64, vr);
      if (tid < 64) ee = lgh[s0 + 64 + tid];
    }

    // ---- S^T = K · Q^T on buf[cur] ----
    const u16* kb = &Ks[cur * 8192];
    f32x4 sacc[4][2];
#pragma unroll
    for (int mt = 0; mt < 4; mt++)
#pragma unroll
      for (int cg = 0; cg < 2; cg++) sacc[mt][cg] = f32x4{0.f, 0.f, 0.f, 0.f};
    __builtin_amdgcn_s_setprio(1);
#pragma unroll
    for (int ks = 0; ks < 4; ks++) {
#pragma unroll
      for (int mt = 0; mt < 4; mt++) {
        FragAB af;
        af.v = *(const bf16x8*)&kb[(mt * 16 + l15) * 128 + 8 * ((4 * ks + kg) ^ l7)];
        sacc[mt][0] = __builtin_amdgcn_mfma_f32_16x16x32_bf16(af.v, qf[0][ks].v, sacc[mt][0], 0, 0, 0);
        sacc[mt][1] = __builtin_amdgcn_mfma_f32_16x16x32_bf16(af.v, qf[1][ks].v, sacc[mt][1], 0, 0, 0);
      }
    }
    __builtin_amdgcn_s_setprio(0);

    // ---- P = (qk)^2 * scale^2 * exp(lgT - lgS), causal mask on diagonal tiles ----
    FragAB pa[2][2];
    const bool need_mask = (it >= 2 * qt);
#pragma unroll
    for (int mt = 0; mt < 4; mt++) {
      f32x4 ev = *(const f32x4*)&eS[cur * 64 + mt * 16 + kg * 4];
#pragma unroll
      for (int cg = 0; cg < 2; cg++) {
        u32 pb[4];
#pragma unroll
        for (int r = 0; r < 4; r++) {
          float x = sacc[mt][cg][r];
          float p = x * x * celg[cg] * ev[r];
          if (need_mask) {
            int s = s0 + mt * 16 + kg * 4 + r;
            p = (s <= myT[cg]) ? p : 0.f;
          }
          nacc[cg] += p;
          pb[r] = __builtin_bit_cast(u32, p) + 0x8000u;  // round-to-nearest bf16 (approx)
        }
        pa[cg][mt >> 1].w[(mt & 1) * 2 + 0] = __builtin_amdgcn_perm(pb[1], pb[0], 0x07060302u);
        pa[cg][mt >> 1].w[(mt & 1) * 2 + 1] = __builtin_amdgcn_perm(pb[3], pb[2], 0x07060302u);
      }
    }

    // ---- Y += P · V ----
    const u16* vb = &Vt[cur * 8192];
    const int x0 = 8 * (kg ^ l7);
    __builtin_amdgcn_s_setprio(1);
#pragma unroll
    for (int ksv = 0; ksv < 2; ksv++) {
      const int xo = x0 ^ (ksv * 32);
#pragma unroll
      for (int nt = 0; nt < 8; nt++) {
        FragAB bfv;
        bfv.v = *(const bf16x8*)&vb[(nt * 16 + l15) * 64 + xo];
        yacc[nt][0] = __builtin_amdgcn_mfma_f32_16x16x32_bf16(pa[0][ksv].v, bfv.v, yacc[nt][0], 0, 0, 0);
        yacc[nt][1] = __builtin_amdgcn_mfma_f32_16x16x32_bf16(pa[1][ksv].v, bfv.v, yacc[nt][1], 0, 0, 0);
      }
    }
    __builtin_amdgcn_s_setprio(0);

    if (hasNext) {  // phase C: drain loads, write next tile's V + gate
      writeV(cur ^ 1, vr);
      if (tid < 64) eS[(cur ^ 1) * 64 + tid] = __expf(-ee);
    }
    __syncthreads();
  }

  // ---- epilogue: unnormalized partials + per-row norm partial ----
  float* yp = half ? y1p : y0p;
  float* np = npart + half * (16 * 2048);
#pragma unroll
  for (int cg = 0; cg < 2; cg++) {
    float nf = nacc[cg];
    nf += __shfl_xor(nf, 16, 64);
    nf += __shfl_xor(nf, 32, 64);
    if (lane < 16) np[hq * 2048 + t0 + wid * 16 + cg * 64 + lane] = nf;
#pragma unroll
    for (int re = 0; re < 4; re++) {
      int trow = t0 + wid * 16 + cg * 64 + kg * 4 + re;
      float* yrow = yp + (size_t)trow * 2048 + hq * 128;
#pragma unroll
      for (int nt = 0; nt < 8; nt++) yrow[nt * 16 + l15] = yacc[nt][cg][re];
    }
  }
}

// ---------------- combine split-K partials + normalize -> bf16 ----------------
__global__ __launch_bounds__(256) void combine_kernel(const float* __restrict__ y0,
                                                      const float* __restrict__ y1,
                                                      const float* __restrict__ npart,
                                                      u16* __restrict__ yb) {
  int i = blockIdx.x * 256 + threadIdx.x;  // float4 index over [2048][2048]
  int e0 = i << 2;
  int t = e0 >> 11;
  int hq = (e0 >> 7) & 15;
  float nn = npart[hq * 2048 + t] + npart[32768 + hq * 2048 + t] + 1e-6f;
  float inv = 1.0f / nn;
  float4 a = ((const float4*)y0)[i];
  float4 b = ((const float4*)y1)[i];
  u32 lo = (u32)f2bf((a.x + b.x) * inv) | ((u32)f2bf((a.y + b.y) * inv) << 16);
  u32 hi = (u32)f2bf((a.z + b.z) * inv) | ((u32)f2bf((a.w + b.w) * inv) << 16);
  ((u32*)yb)[2 * i] = lo;
  ((u32*)yb)[2 * i + 1] = hi;
}

// ---------------- launch ----------------
extern "C" void kernel_launch(void* const* d_in, const int* in_sizes, int n_in,
                              void* d_out, int out_size, void* d_ws, size_t ws_size,
                              hipStream_t stream) {
  (void)in_sizes; (void)n_in; (void)out_size; (void)ws_size;
  const float* hs = (const float*)d_in[0];
  const float* Wq = (const float*)d_in[1];
  const float* Wk = (const float*)d_in[2];
  const float* Wv = (const float*)d_in[3];
  const float* Wg = (const float*)d_in[4];
  const float* Wc = (const float*)d_in[5];
  const float* bc = (const float*)d_in[6];
  float* out = (float*)d_out;

  char* ws = (char*)d_ws;
  const size_t MB = 1024 * 1024;
  u16* slotA  = (u16*)(ws);             // 8MB: WqT then WcT
  u16* slotB  = (u16*)(ws + 8 * MB);    // 8MB: [WkT | WvT] stacked
  u16* hs_bf  = (u16*)(ws + 16 * MB);   // 8MB: hs_bf, later y_bf
  u16* q_bf   = (u16*)(ws + 24 * MB);   // 8MB (column-permuted)
  u16* kv_bf  = (u16*)(ws + 32 * MB);   // 8MB: [K perm (1024) | V linear (1024)] per row
  float* y0p  = (float*)(ws + 40 * MB); // 16MB f32 partial (half 0)
  float* npart = (float*)(ws + 56 * MB);            // 256KB
  float* lgt  = (float*)(ws + 56 * MB + 262144);    // 64KB
  float* logG = (float*)(ws + 56 * MB + 327680);    // 64KB
  float* y1p = out;   // d_out as scratch for half-1 partial (rewritten by final GEMM)
  u16* y_bf = hs_bf;

  conv_bf16_kernel<<<4096, 256, 0, stream>>>(hs, hs_bf, 2048 * 2048 / 4);

  tconv_kernel<<<dim3(64, 64), 256, 0, stream>>>(Wq, slotA, 2048, 2048);
  gemm_bf16<1><<<dim3(16, 16), 512, 0, stream>>>(hs_bf, slotA, q_bf, nullptr, 2048, 2048);

  tconv_kernel<<<dim3(32, 64), 256, 0, stream>>>(Wk, slotB, 2048, 1024);
  tconv_kernel<<<dim3(32, 64), 256, 0, stream>>>(Wv, slotB + (size_t)1024 * 2048, 2048, 1024);
  gemm_bf16<2><<<dim3(16, 16), 512, 0, stream>>>(hs_bf, slotB, kv_bf, nullptr, 2048, 2048);

  gate_kernel<<<512, 256, 0, stream>>>(hs, Wg, lgt);
  cumsum_kernel<<<8, 256, 0, stream>>>(lgt, logG);

  tconv_kernel<<<dim3(64, 64), 256, 0, stream>>>(Wc, slotA, 2048, 2048);

  power_attn<<<dim3(512), 256, 0, stream>>>(q_bf, kv_bf, logG, y0p, y1p, npart);
  combine_kernel<<<4096, 256, 0, stream>>>(y0p, y1p, npart, y_bf);

  gemm_bf16<3><<<dim3(16, 16), 512, 0, stream>>>(y_bf, slotA, out, bc, 2048, 2048);
}

// Round 4
// 199.197 us; speedup vs baseline: 1.8772x; 1.2263x over previous
//
#include <hip/hip_runtime.h>

typedef unsigned short u16;
typedef unsigned int u32;
typedef unsigned long long u64;
typedef __bf16 bf16x8 __attribute__((ext_vector_type(8)));
typedef float f32x4 __attribute__((ext_vector_type(4)));

union FragAB {
  bf16x8 v;
  u16 u[8];
  u32 w[4];
  u64 d2[2];
};

__device__ __forceinline__ u16 f2bf(float f) {
  u32 u = __builtin_bit_cast(u32, f);
  u += 0x7fffu + ((u >> 16) & 1u);
  return (u16)(u >> 16);
}

__device__ __forceinline__ void gload_lds16(const void* g, void* l) {
  __builtin_amdgcn_global_load_lds((__attribute__((address_space(1))) void*)g,
                                   (__attribute__((address_space(3))) void*)l, 16, 0, 0);
}

// column permutation within each 32-group: fragment for (kg) becomes 16 contiguous bytes
__device__ __forceinline__ int permcol(int n) {
  int k = n & 31;
  return (n & ~31) | ((k & 12) << 1) | ((k & 16) >> 2) | (k & 3);
}

// ---------------- fp32 -> bf16 elementwise ----------------
__global__ __launch_bounds__(256) void conv_bf16_kernel(const float* __restrict__ in,
                                                        u16* __restrict__ out, int n4) {
  int i = blockIdx.x * 256 + threadIdx.x;
  if (i >= n4) return;
  float4 v = ((const float4*)in)[i];
  u32 lo = (u32)f2bf(v.x) | ((u32)f2bf(v.y) << 16);
  u32 hi = (u32)f2bf(v.z) | ((u32)f2bf(v.w) << 16);
  ((u32*)out)[2 * i] = lo;
  ((u32*)out)[2 * i + 1] = hi;
}

// ---------------- transpose + convert: out[n][k] = bf16(in[k][n]) ----------------
__global__ __launch_bounds__(256) void tconv_kernel(const float* __restrict__ in,
                                                    u16* __restrict__ out, int K, int N) {
  __shared__ float tile[32][33];
  int col = threadIdx.x & 31;
  int row0 = threadIdx.x >> 5;
  int kb = blockIdx.y * 32, nb = blockIdx.x * 32;
#pragma unroll
  for (int i = 0; i < 4; i++) {
    int r = row0 + i * 8;
    tile[r][col] = in[(size_t)(kb + r) * N + nb + col];
  }
  __syncthreads();
#pragma unroll
  for (int i = 0; i < 4; i++) {
    int r = row0 + i * 8;
    out[(size_t)(nb + r) * K + kb + col] = f2bf(tile[col][r]);
  }
}

// ---------------- merged weight transpose: slab[4096][2048] = [WqT; WkT; WvT] ----------------
// grid (32, 64, 4): z0/z1 = Wq col-halves, z2 = Wk, z3 = Wv
__global__ __launch_bounds__(256) void tconv3_kernel(const float* __restrict__ Wq,
                                                     const float* __restrict__ Wk,
                                                     const float* __restrict__ Wv,
                                                     u16* __restrict__ slab) {
  __shared__ float tile[32][33];
  const int z = blockIdx.z;
  const float* src = (z < 2) ? Wq : (z == 2 ? Wk : Wv);
  const int srcN = (z < 2) ? 2048 : 1024;
  const int colBase = (z == 1) ? 1024 : 0;
  const int dstRowBase = z * 1024;
  int col = threadIdx.x & 31;
  int row0 = threadIdx.x >> 5;
  int kb = blockIdx.y * 32, nb = blockIdx.x * 32;
#pragma unroll
  for (int i = 0; i < 4; i++) {
    int r = row0 + i * 8;
    tile[r][col] = src[(size_t)(kb + r) * srcN + colBase + nb + col];
  }
  __syncthreads();
#pragma unroll
  for (int i = 0; i < 4; i++) {
    int r = row0 + i * 8;
    slab[(size_t)(dstRowBase + nb + r) * 2048 + kb + col] = f2bf(tile[col][r]);
  }
}

// ---------------- gate: lgt[h][t] = log_sigmoid(off + hs[t]·Wg[:,h]) ----------------
__global__ __launch_bounds__(256) void gate_kernel(const float* __restrict__ hs,
                                                   const float* __restrict__ Wg,
                                                   float* __restrict__ lgt) {
  int lane = threadIdx.x & 63, wid = threadIdx.x >> 6;
  int t = blockIdx.x * 4 + wid;
  float acc[8] = {0.f, 0.f, 0.f, 0.f, 0.f, 0.f, 0.f, 0.f};
  for (int c = lane; c < 2048; c += 64) {
    float x = hs[(size_t)t * 2048 + c];
    float4 w0 = *(const float4*)&Wg[c * 8];
    float4 w1 = *(const float4*)&Wg[c * 8 + 4];
    acc[0] += x * w0.x; acc[1] += x * w0.y; acc[2] += x * w0.z; acc[3] += x * w0.w;
    acc[4] += x * w1.x; acc[5] += x * w1.y; acc[6] += x * w1.z; acc[7] += x * w1.w;
  }
#pragma unroll
  for (int h = 0; h < 8; h++) {
    float v = acc[h];
    for (int m = 1; m < 64; m <<= 1) v += __shfl_xor(v, m, 64);
    if (lane == 0) {
      float x = 6.906768f + v;
      lgt[h * 2048 + t] = -log1pf(__expf(-x));
    }
  }
}

// ---------------- inclusive cumsum over t, per head ----------------
__global__ __launch_bounds__(256) void cumsum_kernel(const float* __restrict__ lgt,
                                                     float* __restrict__ logG) {
  int h = blockIdx.x;
  __shared__ float buf[2048];
  for (int i = threadIdx.x; i < 2048; i += 256) buf[i] = lgt[h * 2048 + i];
  __syncthreads();
  for (int off = 1; off < 2048; off <<= 1) {
    float tmp[8];
#pragma unroll
    for (int j = 0; j < 8; j++) {
      int i = threadIdx.x + j * 256;
      tmp[j] = (i >= off) ? buf[i - off] : 0.f;
    }
    __syncthreads();
#pragma unroll
    for (int j = 0; j < 8; j++) {
      int i = threadIdx.x + j * 256;
      buf[i] += tmp[j];
    }
    __syncthreads();
  }
  for (int i = threadIdx.x; i < 2048; i += 256) logG[h * 2048 + i] = buf[i];
}

// ---------------- bf16 MFMA GEMM: C[m][n] = sum_k A[m][k]*BT[n][k] ----------------
// MODE 1: bf16 out, permcol for n < permLim; 1D grid 16*NT, XCD-swizzled.
// MODE 2: split-K x2 -> f32 partials (z=0 -> C0, z=1 -> C1); grid 16*NT*2.
// A row stride = 2048, BT row stride = 2048, output row stride = NT*128.
template <int MODE, int NT>
__global__ __launch_bounds__(512) void gemm_bf16(const u16* __restrict__ A,
                                                 const u16* __restrict__ BT,
                                                 void* __restrict__ C0,
                                                 void* __restrict__ C1,
                                                 int permLim) {
  __shared__ __align__(16) u16 As[128 * 64];
  __shared__ __align__(16) u16 Bs[128 * 64];
  constexpr int nwg = 16 * NT * (MODE == 2 ? 2 : 1);
  constexpr int cpx = nwg >> 3;
  const int raw = (int)blockIdx.x;
  const int wg = (raw & 7) * cpx + (raw >> 3);
  int bx, by, z;
  if constexpr (MODE == 2) {
    z = wg & 1;
    int t = wg >> 1;
    by = t >> 4;
    bx = t & 15;
  } else {
    z = 0;
    by = wg >> 4;
    bx = wg & 15;
  }
  const int kBeg = (MODE == 2) ? z * 1024 : 0;
  const int kEnd = (MODE == 2) ? kBeg + 1024 : 2048;
  constexpr int N = NT * 128;

  const int tid = threadIdx.x;
  const int lane = tid & 63, wid = tid >> 6;
  const int m0 = bx * 128, n0 = by * 128;
  const int wr = wid >> 2, wc = wid & 3;
  const int l15 = lane & 15, kg = lane >> 4;

  f32x4 acc[4][2];
#pragma unroll
  for (int i = 0; i < 4; i++)
#pragma unroll
    for (int j = 0; j < 2; j++) acc[i][j] = f32x4{0.f, 0.f, 0.f, 0.f};

  const int ch0 = (wid * 2) * 64 + lane;
  const int ch1 = ch0 + 64;
  const int r0 = ch0 >> 3, u0 = (ch0 & 7) ^ (r0 & 7);
  const int r1 = ch1 >> 3, u1 = (ch1 & 7) ^ (r1 & 7);
  const u16* Asrc0 = A + (size_t)(m0 + r0) * 2048 + u0 * 8;
  const u16* Asrc1 = A + (size_t)(m0 + r1) * 2048 + u1 * 8;
  const u16* Bsrc0 = BT + (size_t)(n0 + r0) * 2048 + u0 * 8;
  const u16* Bsrc1 = BT + (size_t)(n0 + r1) * 2048 + u1 * 8;
  u16* Adst0 = As + (wid * 2) * 512;
  u16* Bdst0 = Bs + (wid * 2) * 512;

  for (int k0 = kBeg; k0 < kEnd; k0 += 64) {
    __syncthreads();
    gload_lds16(Asrc0 + k0, Adst0);
    gload_lds16(Asrc1 + k0, Adst0 + 512);
    gload_lds16(Bsrc0 + k0, Bdst0);
    gload_lds16(Bsrc1 + k0, Bdst0 + 512);
    __syncthreads();

#pragma unroll
    for (int ks = 0; ks < 2; ks++) {
      FragAB af[4], bfr[2];
      const int ul = ks * 4 + (kg >> 1);
#pragma unroll
      for (int mt = 0; mt < 4; mt++) {
        int row = wr * 64 + mt * 16 + l15;
        int sw = row & 7;
        const u16* p = &As[row * 64 + (kg & 1) * 4];
        af[mt].d2[0] = *(const u64*)&p[(ul ^ sw) << 3];
        af[mt].d2[1] = *(const u64*)&p[((ul + 2) ^ sw) << 3];
      }
#pragma unroll
      for (int nt = 0; nt < 2; nt++) {
        int row = wc * 32 + nt * 16 + l15;
        int sw = row & 7;
        const u16* p = &Bs[row * 64 + (kg & 1) * 4];
        bfr[nt].d2[0] = *(const u64*)&p[(ul ^ sw) << 3];
        bfr[nt].d2[1] = *(const u64*)&p[((ul + 2) ^ sw) << 3];
      }
#pragma unroll
      for (int mt = 0; mt < 4; mt++)
#pragma unroll
        for (int nt = 0; nt < 2; nt++)
          acc[mt][nt] = __builtin_amdgcn_mfma_f32_16x16x32_bf16(af[mt].v, bfr[nt].v, acc[mt][nt], 0, 0, 0);
    }
  }

#pragma unroll
  for (int mt = 0; mt < 4; mt++) {
#pragma unroll
    for (int re = 0; re < 4; re++) {
      int m = m0 + wr * 64 + mt * 16 + kg * 4 + re;
#pragma unroll
      for (int nt = 0; nt < 2; nt++) {
        int n = n0 + wc * 32 + nt * 16 + l15;
        float v = acc[mt][nt][re];
        if constexpr (MODE == 2) {
          float* P = z ? (float*)C1 : (float*)C0;
          P[(size_t)m * N + n] = v;
        } else {
          int nw = (n < permLim) ? permcol(n) : n;
          ((u16*)C0)[(size_t)m * N + nw] = f2bf(v);
        }
      }
    }
  }
}

// ---------------- power attention: Q-tile 128, KV-tile 64, dbuf pipeline ----------------
// QKV layout: qkv[t][4096] = [Qperm(2048) | Kperm(1024) | Vlin(1024)]
__global__ __launch_bounds__(256, 2) void power_attn(const u16* __restrict__ QKV,
                                                     const float* __restrict__ logG,
                                                     float* __restrict__ y0p,
                                                     float* __restrict__ y1p,
                                                     float* __restrict__ npart) {
  __shared__ __align__(16) u16 Ks[2 * 64 * 128];
  __shared__ __align__(16) u16 Vt[2 * 128 * 64];
  __shared__ float eS[2 * 64];

  const int raw = (int)blockIdx.x;
  const int orig = (raw & 7) * 64 + (raw >> 3);
  const int hq = orig >> 5;
  const int j_ = orig & 31;
  const int half = j_ & 1;
  const int bslot = j_ >> 1;
  const int qa = (bslot + (hq >> 1) * 3) & 15;
  const int qt = (hq & 1) ? (15 - qa) : qa;
  const int hk = hq >> 1;
  const int t0 = qt * 128;

  const int tid = threadIdx.x, lane = tid & 63, wid = tid >> 6;
  const int l15 = lane & 15, kg = lane >> 4;
  const int l7 = l15 & 7;

  const int s4 = tid & 15, dgrp = tid >> 4;
  const int ubase = 4 * (s4 >> 3) + (s4 & 3);
  const int vhb = (s4 >> 2) & 1;

  const u16* Kbase = QKV + 2048 + hk * 128;
  const u16* Vbase = QKV + 3072 + hk * 128 + dgrp * 8;
  const float* lgh = logG + hk * 2048;

  FragAB qf[2][4];
  float celg[2];
  int myT[2];
  const float scale2 = 0.0078125f;  // 1/128
#pragma unroll
  for (int cg = 0; cg < 2; cg++) {
    myT[cg] = t0 + wid * 16 + cg * 64 + l15;
    const u16* qrow = QKV + (size_t)myT[cg] * 4096 + hq * 128;
#pragma unroll
    for (int ks = 0; ks < 4; ks++) qf[cg][ks].v = *(const bf16x8*)(qrow + ks * 32 + kg * 8);
    celg[cg] = scale2 * __expf(lgh[myT[cg]]);
  }

  f32x4 yacc[8][2];
#pragma unroll
  for (int i = 0; i < 8; i++)
#pragma unroll
    for (int c = 0; c < 2; c++) yacc[i][c] = f32x4{0.f, 0.f, 0.f, 0.f};
  float nacc[2] = {0.f, 0.f};

  const int itBeg = half ? (qt + 1) : 0;
  const int itEnd = half ? (2 * qt + 2) : (qt + 1);

  auto stageK = [&](int s0, int bb) {
#pragma unroll
    for (int c = 0; c < 4; c++) {
      int ch = (wid * 4 + c) * 64 + lane;
      int row = ch >> 4, du = ch & 15;
      int su = du ^ (row & 7);
      gload_lds16(Kbase + (size_t)(s0 + row) * 4096 + su * 8, &Ks[bb * 8192 + (wid * 4 + c) * 512]);
    }
  };
  auto loadV = [&](int s0, uint4* vr) {
#pragma unroll
    for (int r = 0; r < 4; r++) vr[r] = *(const uint4*)(Vbase + (size_t)(s0 + 4 * s4 + r) * 4096);
  };
  auto writeV = [&](int bb, const uint4* vr) {
    u16* vd = &Vt[bb * 8192];
    const u32* w0 = (const u32*)&vr[0];
    const u32* w1 = (const u32*)&vr[1];
    const u32* w2 = (const u32*)&vr[2];
    const u32* w3 = (const u32*)&vr[3];
#pragma unroll
    for (int i = 0; i < 8; i++) {
      u32 sel = (i & 1) ? 0x07060302u : 0x05040100u;
      u32 lo = __builtin_amdgcn_perm(w1[i >> 1], w0[i >> 1], sel);
      u32 hi = __builtin_amdgcn_perm(w3[i >> 1], w2[i >> 1], sel);
      int d = dgrp * 8 + i;
      int e = d * 64 + 8 * (ubase ^ i) + 4 * vhb;
      *(u64*)&vd[e] = (u64)lo | ((u64)hi << 32);
    }
  };

  {
    uint4 vr[4];
    stageK(itBeg * 64, 0);
    loadV(itBeg * 64, vr);
    float ee = (tid < 64) ? lgh[itBeg * 64 + tid] : 0.f;
    writeV(0, vr);
    if (tid < 64) eS[tid] = __expf(-ee);
  }
  __syncthreads();

  for (int it = itBeg; it < itEnd; it++) {
    const int cur = (it - itBeg) & 1;
    const int s0 = it * 64;
    const bool hasNext = (it + 1 < itEnd);
    uint4 vr[4];
    float ee = 0.f;
    if (hasNext) {
      stageK(s0 + 64, cur ^ 1);
      loadV(s0 + 64, vr);
      if (tid < 64) ee = lgh[s0 + 64 + tid];
    }

    const u16* kb = &Ks[cur * 8192];
    f32x4 sacc[4][2];
#pragma unroll
    for (int mt = 0; mt < 4; mt++)
#pragma unroll
      for (int cg = 0; cg < 2; cg++) sacc[mt][cg] = f32x4{0.f, 0.f, 0.f, 0.f};
    __builtin_amdgcn_s_setprio(1);
#pragma unroll
    for (int ks = 0; ks < 4; ks++) {
#pragma unroll
      for (int mt = 0; mt < 4; mt++) {
        FragAB af;
        af.v = *(const bf16x8*)&kb[(mt * 16 + l15) * 128 + 8 * ((4 * ks + kg) ^ l7)];
        sacc[mt][0] = __builtin_amdgcn_mfma_f32_16x16x32_bf16(af.v, qf[0][ks].v, sacc[mt][0], 0, 0, 0);
        sacc[mt][1] = __builtin_amdgcn_mfma_f32_16x16x32_bf16(af.v, qf[1][ks].v, sacc[mt][1], 0, 0, 0);
      }
    }
    __builtin_amdgcn_s_setprio(0);

    FragAB pa[2][2];
    const bool need_mask = (it >= 2 * qt);
#pragma unroll
    for (int mt = 0; mt < 4; mt++) {
      f32x4 ev = *(const f32x4*)&eS[cur * 64 + mt * 16 + kg * 4];
#pragma unroll
      for (int cg = 0; cg < 2; cg++) {
        u32 pb[4];
#pragma unroll
        for (int r = 0; r < 4; r++) {
          float x = sacc[mt][cg][r];
          float p = x * x * celg[cg] * ev[r];
          if (need_mask) {
            int s = s0 + mt * 16 + kg * 4 + r;
            p = (s <= myT[cg]) ? p : 0.f;
          }
          nacc[cg] += p;
          pb[r] = __builtin_bit_cast(u32, p) + 0x8000u;
        }
        pa[cg][mt >> 1].w[(mt & 1) * 2 + 0] = __builtin_amdgcn_perm(pb[1], pb[0], 0x07060302u);
        pa[cg][mt >> 1].w[(mt & 1) * 2 + 1] = __builtin_amdgcn_perm(pb[3], pb[2], 0x07060302u);
      }
    }

    const u16* vb = &Vt[cur * 8192];
    const int x0 = 8 * (kg ^ l7);
    __builtin_amdgcn_s_setprio(1);
#pragma unroll
    for (int ksv = 0; ksv < 2; ksv++) {
      const int xo = x0 ^ (ksv * 32);
#pragma unroll
      for (int nt = 0; nt < 8; nt++) {
        FragAB bfv;
        bfv.v = *(const bf16x8*)&vb[(nt * 16 + l15) * 64 + xo];
        yacc[nt][0] = __builtin_amdgcn_mfma_f32_16x16x32_bf16(pa[0][ksv].v, bfv.v, yacc[nt][0], 0, 0, 0);
        yacc[nt][1] = __builtin_amdgcn_mfma_f32_16x16x32_bf16(pa[1][ksv].v, bfv.v, yacc[nt][1], 0, 0, 0);
      }
    }
    __builtin_amdgcn_s_setprio(0);

    if (hasNext) {
      writeV(cur ^ 1, vr);
      if (tid < 64) eS[(cur ^ 1) * 64 + tid] = __expf(-ee);
    }
    __syncthreads();
  }

  float* yp = half ? y1p : y0p;
  float* np = npart + half * (16 * 2048);
#pragma unroll
  for (int cg = 0; cg < 2; cg++) {
    float nf = nacc[cg];
    nf += __shfl_xor(nf, 16, 64);
    nf += __shfl_xor(nf, 32, 64);
    if (lane < 16) np[hq * 2048 + t0 + wid * 16 + cg * 64 + lane] = nf;
#pragma unroll
    for (int re = 0; re < 4; re++) {
      int trow = t0 + wid * 16 + cg * 64 + kg * 4 + re;
      float* yrow = yp + (size_t)trow * 2048 + hq * 128;
#pragma unroll
      for (int nt = 0; nt < 8; nt++) yrow[nt * 16 + l15] = yacc[nt][cg][re];
    }
  }
}

// ---------------- combine attention split-K partials + normalize -> bf16 ----------------
__global__ __launch_bounds__(256) void combine_kernel(const float* __restrict__ y0,
                                                      const float* __restrict__ y1,
                                                      const float* __restrict__ npart,
                                                      u16* __restrict__ yb) {
  int i = blockIdx.x * 256 + threadIdx.x;
  int e0 = i << 2;
  int t = e0 >> 11;
  int hq = (e0 >> 7) & 15;
  float nn = npart[hq * 2048 + t] + npart[32768 + hq * 2048 + t] + 1e-6f;
  float inv = 1.0f / nn;
  float4 a = ((const float4*)y0)[i];
  float4 b = ((const float4*)y1)[i];
  u32 lo = (u32)f2bf((a.x + b.x) * inv) | ((u32)f2bf((a.y + b.y) * inv) << 16);
  u32 hi = (u32)f2bf((a.z + b.z) * inv) | ((u32)f2bf((a.w + b.w) * inv) << 16);
  ((u32*)yb)[2 * i] = lo;
  ((u32*)yb)[2 * i + 1] = hi;
}

// ---------------- combine out-GEMM split-K partials + bias (in place on d_out) ----------------
__global__ __launch_bounds__(256) void combine2_kernel(const float* __restrict__ p0,
                                                       float* __restrict__ out,
                                                       const float* __restrict__ bias) {
  int i = blockIdx.x * 256 + threadIdx.x;
  int col = (i << 2) & 2047;
  float4 a = ((const float4*)p0)[i];
  float4 b = ((const float4*)out)[i];
  float4 bb = *(const float4*)&bias[col];
  float4 r;
  r.x = a.x + b.x + bb.x;
  r.y = a.y + b.y + bb.y;
  r.z = a.z + b.z + bb.z;
  r.w = a.w + b.w + bb.w;
  ((float4*)out)[i] = r;
}

// ---------------- launch ----------------
extern "C" void kernel_launch(void* const* d_in, const int* in_sizes, int n_in,
                              void* d_out, int out_size, void* d_ws, size_t ws_size,
                              hipStream_t stream) {
  (void)in_sizes; (void)n_in; (void)out_size; (void)ws_size;
  const float* hs = (const float*)d_in[0];
  const float* Wq = (const float*)d_in[1];
  const float* Wk = (const float*)d_in[2];
  const float* Wv = (const float*)d_in[3];
  const float* Wg = (const float*)d_in[4];
  const float* Wc = (const float*)d_in[5];
  const float* bc = (const float*)d_in[6];
  float* out = (float*)d_out;

  char* ws = (char*)d_ws;
  const size_t MB = 1024 * 1024;
  u16* slab   = (u16*)(ws);              // 16MB: [WqT|WkT|WvT] (4096 rows x 2048); first 8MB reused for WcT
  u16* hs_bf  = (u16*)(ws + 16 * MB);    // 8MB: hs_bf, later y_bf
  u16* qkv_bf = (u16*)(ws + 24 * MB);    // 16MB: [Qperm | Kperm | Vlin] per row (4096 cols)
  float* y0p  = (float*)(ws + 40 * MB);  // 16MB: attn half-0 partial, later out-GEMM partial 0
  float* npart = (float*)(ws + 56 * MB);            // 256KB
  float* lgt  = (float*)(ws + 56 * MB + 262144);    // 64KB
  float* logG = (float*)(ws + 56 * MB + 327680);    // 64KB
  float* y1p = out;   // d_out as scratch for attn half-1 partial
  u16* y_bf = hs_bf;
  u16* WcT = slab;

  conv_bf16_kernel<<<4096, 256, 0, stream>>>(hs, hs_bf, 2048 * 2048 / 4);
  tconv3_kernel<<<dim3(32, 64, 4), 256, 0, stream>>>(Wq, Wk, Wv, slab);

  // merged QKV GEMM: [2048 x 4096] = hs_bf @ slab^T, 512 blocks (2/CU)
  gemm_bf16<1, 32><<<512, 512, 0, stream>>>(hs_bf, slab, qkv_bf, nullptr, 3072);

  gate_kernel<<<512, 256, 0, stream>>>(hs, Wg, lgt);
  cumsum_kernel<<<8, 256, 0, stream>>>(lgt, logG);

  tconv_kernel<<<dim3(64, 64), 256, 0, stream>>>(Wc, WcT, 2048, 2048);

  power_attn<<<dim3(512), 256, 0, stream>>>(qkv_bf, logG, y0p, y1p, npart);
  combine_kernel<<<4096, 256, 0, stream>>>(y0p, y1p, npart, y_bf);

  // out GEMM split-K x2: partial0 -> y0p, partial1 -> d_out; then add + bias
  gemm_bf16<2, 16><<<512, 512, 0, stream>>>(y_bf, WcT, y0p, out, 0);
  combine2_kernel<<<4096, 256, 0, stream>>>(y0p, out, bc);
}

// Round 5
// 164.151 us; speedup vs baseline: 2.2780x; 1.2135x over previous
//
#include <hip/hip_runtime.h>

typedef unsigned short u16;
typedef unsigned int u32;
typedef unsigned long long u64;
typedef __bf16 bf16x8 __attribute__((ext_vector_type(8)));
typedef float f32x4 __attribute__((ext_vector_type(4)));

union FragAB {
  bf16x8 v;
  u16 u[8];
  u32 w[4];
  u64 d2[2];
};

__device__ __forceinline__ u16 f2bf(float f) {
  u32 u = __builtin_bit_cast(u32, f);
  u += 0x7fffu + ((u >> 16) & 1u);
  return (u16)(u >> 16);
}

__device__ __forceinline__ void gload_lds16(const void* g, void* l) {
  __builtin_amdgcn_global_load_lds((__attribute__((address_space(1))) void*)g,
                                   (__attribute__((address_space(3))) void*)l, 16, 0, 0);
}

// column permutation within each 32-group: fragment for (kg) becomes 16 contiguous bytes
// e = 8*((k&15)>>2) + 4*(k>>4) + (k&3)
__device__ __forceinline__ int permcol(int n) {
  int k = n & 31;
  return (n & ~31) | ((k & 12) << 1) | ((k & 16) >> 2) | (k & 3);
}

// ---------------- fp32 -> bf16, k-permuted (p-layout) ----------------
__global__ __launch_bounds__(256) void conv_perm_kernel(const float* __restrict__ in,
                                                        u16* __restrict__ out, int n4) {
  int i = blockIdx.x * 256 + threadIdx.x;
  if (i >= n4) return;
  float4 v = ((const float4*)in)[i];
  u64 pk = (u64)f2bf(v.x) | ((u64)f2bf(v.y) << 16) | ((u64)f2bf(v.z) << 32) |
           ((u64)f2bf(v.w) << 48);
  int col = (i << 2) & 2047;
  int g = (col >> 2) & 7;
  int ncol = (col & ~31) | ((2 * (g & 3) + (g >> 2)) << 2);
  size_t row = (size_t)(i >> 9);
  *(u64*)&out[row * 2048 + ncol] = pk;
}

// ---------------- transpose + convert (k-permuted): out[n][perm(k)] = bf16(in[k][n]) ----------------
__global__ __launch_bounds__(256) void tconv_kernel(const float* __restrict__ in,
                                                    u16* __restrict__ out, int K, int N) {
  __shared__ float tile[32][33];
  int col = threadIdx.x & 31;
  int row0 = threadIdx.x >> 5;
  int kb = blockIdx.y * 32, nb = blockIdx.x * 32;
  int pcol = permcol(col);
#pragma unroll
  for (int i = 0; i < 4; i++) {
    int r = row0 + i * 8;
    tile[r][col] = in[(size_t)(kb + r) * N + nb + col];
  }
  __syncthreads();
#pragma unroll
  for (int i = 0; i < 4; i++) {
    int r = row0 + i * 8;
    out[(size_t)(nb + r) * K + kb + pcol] = f2bf(tile[col][r]);
  }
}

// ---------------- merged weight transpose (k-permuted): slab[4096][2048] ----------------
__global__ __launch_bounds__(256) void tconv3_kernel(const float* __restrict__ Wq,
                                                     const float* __restrict__ Wk,
                                                     const float* __restrict__ Wv,
                                                     u16* __restrict__ slab) {
  __shared__ float tile[32][33];
  const int z = blockIdx.z;
  const float* src = (z < 2) ? Wq : (z == 2 ? Wk : Wv);
  const int srcN = (z < 2) ? 2048 : 1024;
  const int colBase = (z == 1) ? 1024 : 0;
  const int dstRowBase = z * 1024;
  int col = threadIdx.x & 31;
  int row0 = threadIdx.x >> 5;
  int kb = blockIdx.y * 32, nb = blockIdx.x * 32;
  int pcol = permcol(col);
#pragma unroll
  for (int i = 0; i < 4; i++) {
    int r = row0 + i * 8;
    tile[r][col] = src[(size_t)(kb + r) * srcN + colBase + nb + col];
  }
  __syncthreads();
#pragma unroll
  for (int i = 0; i < 4; i++) {
    int r = row0 + i * 8;
    slab[(size_t)(dstRowBase + nb + r) * 2048 + kb + pcol] = f2bf(tile[col][r]);
  }
}

// ---------------- gate: lgt[h][t] = log_sigmoid(off + hs[t]·Wg[:,h]) ----------------
__global__ __launch_bounds__(256) void gate_kernel(const float* __restrict__ hs,
                                                   const float* __restrict__ Wg,
                                                   float* __restrict__ lgt) {
  int lane = threadIdx.x & 63, wid = threadIdx.x >> 6;
  int t = blockIdx.x * 4 + wid;
  float acc[8] = {0.f, 0.f, 0.f, 0.f, 0.f, 0.f, 0.f, 0.f};
  for (int c = lane; c < 2048; c += 64) {
    float x = hs[(size_t)t * 2048 + c];
    float4 w0 = *(const float4*)&Wg[c * 8];
    float4 w1 = *(const float4*)&Wg[c * 8 + 4];
    acc[0] += x * w0.x; acc[1] += x * w0.y; acc[2] += x * w0.z; acc[3] += x * w0.w;
    acc[4] += x * w1.x; acc[5] += x * w1.y; acc[6] += x * w1.z; acc[7] += x * w1.w;
  }
#pragma unroll
  for (int h = 0; h < 8; h++) {
    float v = acc[h];
    for (int m = 1; m < 64; m <<= 1) v += __shfl_xor(v, m, 64);
    if (lane == 0) {
      float x = 6.906768f + v;
      lgt[h * 2048 + t] = -log1pf(__expf(-x));
    }
  }
}

// ---------------- inclusive cumsum over t, per head ----------------
__global__ __launch_bounds__(256) void cumsum_kernel(const float* __restrict__ lgt,
                                                     float* __restrict__ logG) {
  int h = blockIdx.x;
  __shared__ float buf[2048];
  for (int i = threadIdx.x; i < 2048; i += 256) buf[i] = lgt[h * 2048 + i];
  __syncthreads();
  for (int off = 1; off < 2048; off <<= 1) {
    float tmp[8];
#pragma unroll
    for (int j = 0; j < 8; j++) {
      int i = threadIdx.x + j * 256;
      tmp[j] = (i >= off) ? buf[i - off] : 0.f;
    }
    __syncthreads();
#pragma unroll
    for (int j = 0; j < 8; j++) {
      int i = threadIdx.x + j * 256;
      buf[i] += tmp[j];
    }
    __syncthreads();
  }
  for (int i = threadIdx.x; i < 2048; i += 256) logG[h * 2048 + i] = buf[i];
}

// ---------------- bf16 MFMA GEMM v2: p-layout inputs, b128 frags, 2-phase dbuf ----------------
// MODE 1: bf16 out, permcol for n < permLim; grid 16*NT, XCD-swizzled.
// MODE 2: split-K x2 -> f32 partials (z=0 -> C0, z=1 -> C1); grid 16*NT*2.
template <int MODE, int NT>
__global__ __launch_bounds__(512, 4) void gemm_v2(const u16* __restrict__ A,
                                                  const u16* __restrict__ BT,
                                                  void* __restrict__ C0,
                                                  void* __restrict__ C1,
                                                  int permLim) {
  __shared__ __align__(16) u16 As[2 * 128 * 64];
  __shared__ __align__(16) u16 Bs[2 * 128 * 64];
  constexpr int nwg = 16 * NT * (MODE == 2 ? 2 : 1);
  constexpr int cpx = nwg >> 3;
  const int raw = (int)blockIdx.x;
  const int wg = (raw & 7) * cpx + (raw >> 3);
  int bx, by, z;
  if constexpr (MODE == 2) {
    z = wg & 1;
    int t = wg >> 1;
    by = t >> 4;
    bx = t & 15;
  } else {
    z = 0;
    by = wg >> 4;
    bx = wg & 15;
  }
  const int kBeg = (MODE == 2) ? z * 1024 : 0;
  const int kEnd = (MODE == 2) ? kBeg + 1024 : 2048;
  constexpr int N = NT * 128;

  const int tid = threadIdx.x;
  const int lane = tid & 63, wid = tid >> 6;
  const int m0 = bx * 128, n0 = by * 128;
  const int wr = wid >> 2, wc = wid & 3;
  const int l15 = lane & 15, kg = lane >> 4;

  f32x4 acc[4][2];
#pragma unroll
  for (int i = 0; i < 4; i++)
#pragma unroll
    for (int j = 0; j < 2; j++) acc[i][j] = f32x4{0.f, 0.f, 0.f, 0.f};

  // staging: 1024 16B-units per matrix; thread does 2 per matrix.
  // LDS[row][du] = global[row][du ^ (row&7)] (p-layout source)
  const int c0 = (wid * 2) * 64 + lane;
  const int c1 = c0 + 64;
  const int r0 = c0 >> 3, s0u = (c0 & 7) ^ (r0 & 7);
  const int r1 = c1 >> 3, s1u = (c1 & 7) ^ (r1 & 7);
  const u16* Asrc0 = A + (size_t)(m0 + r0) * 2048 + s0u * 8;
  const u16* Asrc1 = A + (size_t)(m0 + r1) * 2048 + s1u * 8;
  const u16* Bsrc0 = BT + (size_t)(n0 + r0) * 2048 + s0u * 8;
  const u16* Bsrc1 = BT + (size_t)(n0 + r1) * 2048 + s1u * 8;

  auto stage = [&](int buf, int k0) {
    u16* Ad = As + buf * 8192 + (wid * 2) * 512;
    u16* Bd = Bs + buf * 8192 + (wid * 2) * 512;
    gload_lds16(Asrc0 + k0, Ad);
    gload_lds16(Asrc1 + k0, Ad + 512);
    gload_lds16(Bsrc0 + k0, Bd);
    gload_lds16(Bsrc1 + k0, Bd + 512);
  };

  stage(0, kBeg);
  __syncthreads();

  int cur = 0;
  for (int k0 = kBeg; k0 < kEnd; k0 += 64) {
    if (k0 + 64 < kEnd) stage(cur ^ 1, k0 + 64);  // issue next tile (hidden under compute)
    const u16* Ab = As + cur * 8192;
    const u16* Bb = Bs + cur * 8192;
#pragma unroll
    for (int ks = 0; ks < 2; ks++) {
      FragAB af[4], bfr[2];
#pragma unroll
      for (int mt = 0; mt < 4; mt++) {
        int row = wr * 64 + mt * 16 + l15;
        af[mt].v = *(const bf16x8*)&Ab[row * 64 + 8 * ((ks * 4 + kg) ^ (row & 7))];
      }
#pragma unroll
      for (int nt = 0; nt < 2; nt++) {
        int row = wc * 32 + nt * 16 + l15;
        bfr[nt].v = *(const bf16x8*)&Bb[row * 64 + 8 * ((ks * 4 + kg) ^ (row & 7))];
      }
#pragma unroll
      for (int mt = 0; mt < 4; mt++)
#pragma unroll
        for (int nt = 0; nt < 2; nt++)
          acc[mt][nt] = __builtin_amdgcn_mfma_f32_16x16x32_bf16(af[mt].v, bfr[nt].v, acc[mt][nt], 0, 0, 0);
    }
    __syncthreads();  // drains vmcnt for next buffer + protects LDS reuse
    cur ^= 1;
  }

#pragma unroll
  for (int mt = 0; mt < 4; mt++) {
#pragma unroll
    for (int re = 0; re < 4; re++) {
      int m = m0 + wr * 64 + mt * 16 + kg * 4 + re;
#pragma unroll
      for (int nt = 0; nt < 2; nt++) {
        int n = n0 + wc * 32 + nt * 16 + l15;
        float v = acc[mt][nt][re];
        if constexpr (MODE == 2) {
          float* P = z ? (float*)C1 : (float*)C0;
          P[(size_t)m * N + n] = v;
        } else {
          int nw = (n < permLim) ? permcol(n) : n;
          ((u16*)C0)[(size_t)m * N + nw] = f2bf(v);
        }
      }
    }
  }
}

// ---------------- power attention: Q-tile 128, KV-tile 64, dbuf pipeline ----------------
// QKV layout: qkv[t][4096] = [Qperm(2048) | Kperm(1024) | Vlin(1024)]
__global__ __launch_bounds__(256, 2) void power_attn(const u16* __restrict__ QKV,
                                                     const float* __restrict__ logG,
                                                     float* __restrict__ y0p,
                                                     float* __restrict__ y1p,
                                                     float* __restrict__ npart) {
  __shared__ __align__(16) u16 Ks[2 * 64 * 128];
  __shared__ __align__(16) u16 Vt[2 * 128 * 64];
  __shared__ float eS[2 * 64];

  const int raw = (int)blockIdx.x;
  const int orig = (raw & 7) * 64 + (raw >> 3);
  const int hq = orig >> 5;
  const int j_ = orig & 31;
  const int half = j_ & 1;
  const int bslot = j_ >> 1;
  const int qa = (bslot + (hq >> 1) * 3) & 15;
  const int qt = (hq & 1) ? (15 - qa) : qa;
  const int hk = hq >> 1;
  const int t0 = qt * 128;

  const int tid = threadIdx.x, lane = tid & 63, wid = tid >> 6;
  const int l15 = lane & 15, kg = lane >> 4;
  const int l7 = l15 & 7;

  const int s4 = tid & 15, dgrp = tid >> 4;
  const int ubase = 4 * (s4 >> 3) + (s4 & 3);
  const int vhb = (s4 >> 2) & 1;

  const u16* Kbase = QKV + 2048 + hk * 128;
  const u16* Vbase = QKV + 3072 + hk * 128 + dgrp * 8;
  const float* lgh = logG + hk * 2048;

  FragAB qf[2][4];
  float celg[2];
  int myT[2];
  const float scale2 = 0.0078125f;  // 1/128
#pragma unroll
  for (int cg = 0; cg < 2; cg++) {
    myT[cg] = t0 + wid * 16 + cg * 64 + l15;
    const u16* qrow = QKV + (size_t)myT[cg] * 4096 + hq * 128;
#pragma unroll
    for (int ks = 0; ks < 4; ks++) qf[cg][ks].v = *(const bf16x8*)(qrow + ks * 32 + kg * 8);
    celg[cg] = scale2 * __expf(lgh[myT[cg]]);
  }

  f32x4 yacc[8][2];
#pragma unroll
  for (int i = 0; i < 8; i++)
#pragma unroll
    for (int c = 0; c < 2; c++) yacc[i][c] = f32x4{0.f, 0.f, 0.f, 0.f};
  float nacc[2] = {0.f, 0.f};

  const int itBeg = half ? (qt + 1) : 0;
  const int itEnd = half ? (2 * qt + 2) : (qt + 1);

  auto stageK = [&](int s0, int bb) {
#pragma unroll
    for (int c = 0; c < 4; c++) {
      int ch = (wid * 4 + c) * 64 + lane;
      int row = ch >> 4, du = ch & 15;
      int su = du ^ (row & 7);
      gload_lds16(Kbase + (size_t)(s0 + row) * 4096 + su * 8, &Ks[bb * 8192 + (wid * 4 + c) * 512]);
    }
  };
  auto loadV = [&](int s0, uint4* vr) {
#pragma unroll
    for (int r = 0; r < 4; r++) vr[r] = *(const uint4*)(Vbase + (size_t)(s0 + 4 * s4 + r) * 4096);
  };
  auto writeV = [&](int bb, const uint4* vr) {
    u16* vd = &Vt[bb * 8192];
    const u32* w0 = (const u32*)&vr[0];
    const u32* w1 = (const u32*)&vr[1];
    const u32* w2 = (const u32*)&vr[2];
    const u32* w3 = (const u32*)&vr[3];
#pragma unroll
    for (int i = 0; i < 8; i++) {
      u32 sel = (i & 1) ? 0x07060302u : 0x05040100u;
      u32 lo = __builtin_amdgcn_perm(w1[i >> 1], w0[i >> 1], sel);
      u32 hi = __builtin_amdgcn_perm(w3[i >> 1], w2[i >> 1], sel);
      int d = dgrp * 8 + i;
      int e = d * 64 + 8 * (ubase ^ i) + 4 * vhb;
      *(u64*)&vd[e] = (u64)lo | ((u64)hi << 32);
    }
  };

  {
    uint4 vr[4];
    stageK(itBeg * 64, 0);
    loadV(itBeg * 64, vr);
    float ee = (tid < 64) ? lgh[itBeg * 64 + tid] : 0.f;
    writeV(0, vr);
    if (tid < 64) eS[tid] = __expf(-ee);
  }
  __syncthreads();

  for (int it = itBeg; it < itEnd; it++) {
    const int cur = (it - itBeg) & 1;
    const int s0 = it * 64;
    const bool hasNext = (it + 1 < itEnd);
    uint4 vr[4];
    float ee = 0.f;
    if (hasNext) {
      stageK(s0 + 64, cur ^ 1);
      loadV(s0 + 64, vr);
      if (tid < 64) ee = lgh[s0 + 64 + tid];
    }

    const u16* kb = &Ks[cur * 8192];
    f32x4 sacc[4][2];
#pragma unroll
    for (int mt = 0; mt < 4; mt++)
#pragma unroll
      for (int cg = 0; cg < 2; cg++) sacc[mt][cg] = f32x4{0.f, 0.f, 0.f, 0.f};
    __builtin_amdgcn_s_setprio(1);
#pragma unroll
    for (int ks = 0; ks < 4; ks++) {
#pragma unroll
      for (int mt = 0; mt < 4; mt++) {
        FragAB af;
        af.v = *(const bf16x8*)&kb[(mt * 16 + l15) * 128 + 8 * ((4 * ks + kg) ^ l7)];
        sacc[mt][0] = __builtin_amdgcn_mfma_f32_16x16x32_bf16(af.v, qf[0][ks].v, sacc[mt][0], 0, 0, 0);
        sacc[mt][1] = __builtin_amdgcn_mfma_f32_16x16x32_bf16(af.v, qf[1][ks].v, sacc[mt][1], 0, 0, 0);
      }
    }
    __builtin_amdgcn_s_setprio(0);

    FragAB pa[2][2];
    const bool need_mask = (it >= 2 * qt);
#pragma unroll
    for (int mt = 0; mt < 4; mt++) {
      f32x4 ev = *(const f32x4*)&eS[cur * 64 + mt * 16 + kg * 4];
#pragma unroll
      for (int cg = 0; cg < 2; cg++) {
        u32 pb[4];
#pragma unroll
        for (int r = 0; r < 4; r++) {
          float x = sacc[mt][cg][r];
          float p = x * x * celg[cg] * ev[r];
          if (need_mask) {
            int s = s0 + mt * 16 + kg * 4 + r;
            p = (s <= myT[cg]) ? p : 0.f;
          }
          nacc[cg] += p;
          pb[r] = __builtin_bit_cast(u32, p) + 0x8000u;
        }
        pa[cg][mt >> 1].w[(mt & 1) * 2 + 0] = __builtin_amdgcn_perm(pb[1], pb[0], 0x07060302u);
        pa[cg][mt >> 1].w[(mt & 1) * 2 + 1] = __builtin_amdgcn_perm(pb[3], pb[2], 0x07060302u);
      }
    }

    const u16* vb = &Vt[cur * 8192];
    const int x0 = 8 * (kg ^ l7);
    __builtin_amdgcn_s_setprio(1);
#pragma unroll
    for (int ksv = 0; ksv < 2; ksv++) {
      const int xo = x0 ^ (ksv * 32);
#pragma unroll
      for (int nt = 0; nt < 8; nt++) {
        FragAB bfv;
        bfv.v = *(const bf16x8*)&vb[(nt * 16 + l15) * 64 + xo];
        yacc[nt][0] = __builtin_amdgcn_mfma_f32_16x16x32_bf16(pa[0][ksv].v, bfv.v, yacc[nt][0], 0, 0, 0);
        yacc[nt][1] = __builtin_amdgcn_mfma_f32_16x16x32_bf16(pa[1][ksv].v, bfv.v, yacc[nt][1], 0, 0, 0);
      }
    }
    __builtin_amdgcn_s_setprio(0);

    if (hasNext) {
      writeV(cur ^ 1, vr);
      if (tid < 64) eS[(cur ^ 1) * 64 + tid] = __expf(-ee);
    }
    __syncthreads();
  }

  float* yp = half ? y1p : y0p;
  float* np = npart + half * (16 * 2048);
#pragma unroll
  for (int cg = 0; cg < 2; cg++) {
    float nf = nacc[cg];
    nf += __shfl_xor(nf, 16, 64);
    nf += __shfl_xor(nf, 32, 64);
    if (lane < 16) np[hq * 2048 + t0 + wid * 16 + cg * 64 + lane] = nf;
#pragma unroll
    for (int re = 0; re < 4; re++) {
      int trow = t0 + wid * 16 + cg * 64 + kg * 4 + re;
      float* yrow = yp + (size_t)trow * 2048 + hq * 128;
#pragma unroll
      for (int nt = 0; nt < 8; nt++) yrow[nt * 16 + l15] = yacc[nt][cg][re];
    }
  }
}

// ---------------- combine attention split-K partials + normalize -> bf16 (p-layout) ----------------
__global__ __launch_bounds__(256) void combine_kernel(const float* __restrict__ y0,
                                                      const float* __restrict__ y1,
                                                      const float* __restrict__ npart,
                                                      u16* __restrict__ yb) {
  int i = blockIdx.x * 256 + threadIdx.x;
  int e0 = i << 2;
  int t = e0 >> 11;
  int hq = (e0 >> 7) & 15;
  float nn = npart[hq * 2048 + t] + npart[32768 + hq * 2048 + t] + 1e-6f;
  float inv = 1.0f / nn;
  float4 a = ((const float4*)y0)[i];
  float4 b = ((const float4*)y1)[i];
  u64 pk = (u64)f2bf((a.x + b.x) * inv) | ((u64)f2bf((a.y + b.y) * inv) << 16) |
           ((u64)f2bf((a.z + b.z) * inv) << 32) | ((u64)f2bf((a.w + b.w) * inv) << 48);
  int col = e0 & 2047;
  int g = (col >> 2) & 7;
  int ncol = (col & ~31) | ((2 * (g & 3) + (g >> 2)) << 2);
  *(u64*)&yb[(size_t)t * 2048 + ncol] = pk;
}

// ---------------- combine out-GEMM split-K partials + bias (in place on d_out) ----------------
__global__ __launch_bounds__(256) void combine2_kernel(const float* __restrict__ p0,
                                                       float* __restrict__ out,
                                                       const float* __restrict__ bias) {
  int i = blockIdx.x * 256 + threadIdx.x;
  int col = (i << 2) & 2047;
  float4 a = ((const float4*)p0)[i];
  float4 b = ((const float4*)out)[i];
  float4 bb = *(const float4*)&bias[col];
  float4 r;
  r.x = a.x + b.x + bb.x;
  r.y = a.y + b.y + bb.y;
  r.z = a.z + b.z + bb.z;
  r.w = a.w + b.w + bb.w;
  ((float4*)out)[i] = r;
}

// ---------------- launch ----------------
extern "C" void kernel_launch(void* const* d_in, const int* in_sizes, int n_in,
                              void* d_out, int out_size, void* d_ws, size_t ws_size,
                              hipStream_t stream) {
  (void)in_sizes; (void)n_in; (void)out_size; (void)ws_size;
  const float* hs = (const float*)d_in[0];
  const float* Wq = (const float*)d_in[1];
  const float* Wk = (const float*)d_in[2];
  const float* Wv = (const float*)d_in[3];
  const float* Wg = (const float*)d_in[4];
  const float* Wc = (const float*)d_in[5];
  const float* bc = (const float*)d_in[6];
  float* out = (float*)d_out;

  char* ws = (char*)d_ws;
  const size_t MB = 1024 * 1024;
  u16* slab   = (u16*)(ws);              // 16MB: [WqT|WkT|WvT] p-layout; first 8MB reused for WcT
  u16* hs_bf  = (u16*)(ws + 16 * MB);    // 8MB: hs p-layout, later y_bf p-layout
  u16* qkv_bf = (u16*)(ws + 24 * MB);    // 16MB: [Qperm | Kperm | Vlin] per row (4096 cols)
  float* y0p  = (float*)(ws + 40 * MB);  // 16MB: attn half-0 partial, later out-GEMM partial 0
  float* npart = (float*)(ws + 56 * MB);            // 256KB
  float* lgt  = (float*)(ws + 56 * MB + 262144);    // 64KB
  float* logG = (float*)(ws + 56 * MB + 327680);    // 64KB
  float* y1p = out;   // d_out as scratch for attn half-1 partial
  u16* y_bf = hs_bf;
  u16* WcT = slab;

  conv_perm_kernel<<<4096, 256, 0, stream>>>(hs, hs_bf, 2048 * 2048 / 4);
  tconv3_kernel<<<dim3(32, 64, 4), 256, 0, stream>>>(Wq, Wk, Wv, slab);

  // merged QKV GEMM: [2048 x 4096] = hs_bf @ slab^T, 512 blocks (2/CU)
  gemm_v2<1, 32><<<512, 512, 0, stream>>>(hs_bf, slab, qkv_bf, nullptr, 3072);

  gate_kernel<<<512, 256, 0, stream>>>(hs, Wg, lgt);
  cumsum_kernel<<<8, 256, 0, stream>>>(lgt, logG);

  tconv_kernel<<<dim3(64, 64), 256, 0, stream>>>(Wc, WcT, 2048, 2048);

  power_attn<<<dim3(512), 256, 0, stream>>>(qkv_bf, logG, y0p, y1p, npart);
  combine_kernel<<<4096, 256, 0, stream>>>(y0p, y1p, npart, y_bf);

  // out GEMM split-K x2: partial0 -> y0p, partial1 -> d_out; then add + bias
  gemm_v2<2, 16><<<512, 512, 0, stream>>>(y_bf, WcT, y0p, out, 0);
  combine2_kernel<<<4096, 256, 0, stream>>>(y0p, out, bc);
}